// Round 9
// baseline (423.355 us; speedup 1.0000x reference)
//
#include <hip/hip_runtime.h>
#include <math.h>
#include <stdint.h>

#define SEQ   1024
#define CIN   7
#define NB    8
#define BC    56          // NB*CIN
#define NP    128         // patches
#define DM    512
#define NH    8
#define DH    64
#define DFF   2048
#define U     25
#define NTOK  (BC*NP)     // 7168
#define PE_COEF (-9.210340371976184f / 512.0f)  // -ln(10000)/DM
#define HKB   256         // head: K elems per split-K block
#define HNB   256         // head: number of split-K blocks (HKB*HNB = 65536)

typedef __attribute__((ext_vector_type(8))) short short8;
typedef __attribute__((ext_vector_type(4))) float f32x4;

__device__ __forceinline__ short f2bf(float x) {
    union { float f; uint32_t u; } v; v.f = x;
    uint32_t r = v.u + 0x7FFFu + ((v.u >> 16) & 1u);
    return (short)(r >> 16);
}
__device__ __forceinline__ float bf2f(short x) {
    union { uint32_t u; float f; } v; v.u = ((uint32_t)(uint16_t)x) << 16;
    return v.f;
}

__device__ __forceinline__ void gl_lds16(const void* g, void* s) {
    __builtin_amdgcn_global_load_lds((const __attribute__((address_space(1))) void*)g,
                                     (__attribute__((address_space(3))) void*)s, 16, 0, 0);
}

// ---------------- stats: per (b,c) mean/std over SEQ ----------------
__global__ void stats_kernel(const float* __restrict__ x, float* __restrict__ mean,
                             float* __restrict__ stdv) {
    int bc = blockIdx.x; int b = bc / CIN, c = bc % CIN;
    const float* base = x + (size_t)b * SEQ * CIN + c;
    float s = 0.f, ss = 0.f;
    for (int i = threadIdx.x; i < SEQ; i += 256) {
        float v = base[(size_t)i * CIN];
        s += v; ss += v * v;
    }
    __shared__ float rs[256], rss[256];
    rs[threadIdx.x] = s; rss[threadIdx.x] = ss; __syncthreads();
    for (int o = 128; o > 0; o >>= 1) {
        if (threadIdx.x < o) { rs[threadIdx.x] += rs[threadIdx.x + o]; rss[threadIdx.x] += rss[threadIdx.x + o]; }
        __syncthreads();
    }
    if (threadIdx.x == 0) {
        float m = rs[0] / SEQ;
        float v = rss[0] / SEQ - m * m;
        mean[bc] = m;
        stdv[bc] = sqrtf(v + 1e-5f);
    }
}

// ---------------- threefry2x32-20 (JAX PRNG) ----------------
__device__ __forceinline__ void tf_round(uint32_t& x0, uint32_t& x1, uint32_t r) {
    x0 += x1; x1 = (x1 << r) | (x1 >> (32u - r)); x1 ^= x0;
}
__device__ void threefry2x32(uint32_t k0, uint32_t k1, uint32_t x0, uint32_t x1,
                             uint32_t& o0, uint32_t& o1) {
    uint32_t ks[3] = { k0, k1, k0 ^ k1 ^ 0x1BD11BDAu };
    x0 += ks[0]; x1 += ks[1];
    const uint32_t rotA[4] = {13u, 15u, 26u, 6u}, rotB[4] = {17u, 29u, 16u, 24u};
    #pragma unroll
    for (int i = 0; i < 5; i++) {
        const uint32_t* rr = (i & 1) ? rotB : rotA;
        tf_round(x0, x1, rr[0]); tf_round(x0, x1, rr[1]);
        tf_round(x0, x1, rr[2]); tf_round(x0, x1, rr[3]);
        x0 += ks[(i + 1) % 3];
        x1 += ks[(i + 2) % 3] + (uint32_t)(i + 1);
    }
    o0 = x0; o1 = x1;
}

// ---------------- fused prep: pack QKV weights, convert Wo/c1W/c2W, samp ----------------
__global__ void prep_weights(const float* __restrict__ Wq, const float* __restrict__ Wk,
                             const float* __restrict__ Wv, const float* __restrict__ bq,
                             const float* __restrict__ bk, const float* __restrict__ bv,
                             const float* __restrict__ Wo, const float* __restrict__ c1W,
                             const float* __restrict__ c2W,
                             short* __restrict__ wqkv, float* __restrict__ bqkv,
                             short* __restrict__ wo_b, short* __restrict__ c1w_b,
                             short* __restrict__ c2w_b, int* __restrict__ samp) {
    int blk = blockIdx.x, tid = threadIdx.x;
    if (blk < 1536) {                       // pack_qkv: 2*1536*128 float4 slots
        int idx = blk * 256 + tid;
        int k4 = idx & 127;
        int n  = (idx >> 7) % 1536;
        int l  = idx / (1536 * 128);
        int sel3 = n >> 9;
        int nn = n & 511;
        const float* src = sel3 == 0 ? Wq : sel3 == 1 ? Wk : Wv;
        float4 v = *(const float4*)(src + ((size_t)l * DM + nn) * DM + k4 * 4);
        short4 o; o.x = f2bf(v.x); o.y = f2bf(v.y); o.z = f2bf(v.z); o.w = f2bf(v.w);
        *(short4*)(wqkv + ((size_t)l * 1536 + n) * DM + k4 * 4) = o;
        if (k4 == 0) {
            const float* bsrc = sel3 == 0 ? bq : sel3 == 1 ? bk : bv;
            bqkv[l * 1536 + n] = bsrc[l * DM + nn];
        }
    } else if (blk < 6144) {                // converts
        const float* in; short* out; int i;
        if (blk < 2048)      { in = Wo;  out = wo_b;  i = (blk - 1536) * 256 + tid; }
        else if (blk < 4096) { in = c1W; out = c1w_b; i = (blk - 2048) * 256 + tid; }
        else                 { in = c2W; out = c2w_b; i = (blk - 4096) * 256 + tid; }
        float4 v = ((const float4*)in)[i];
        short4 o; o.x = f2bf(v.x); o.y = f2bf(v.y); o.z = f2bf(v.z); o.w = f2bf(v.w);
        ((short4*)out)[i] = o;
    } else {                                 // samp: 2 blocks
        int l = blk - 6144;
        uint32_t s0, s1; threefry2x32(0u, 42u, 0u, (uint32_t)l, s0, s1);
        uint32_t a0, a1, b0, b1;
        threefry2x32(s0, s1, 0u, 2u, a0, a1);
        threefry2x32(s0, s1, 1u, 3u, b0, b1);
        uint32_t k20 = a1, k21 = b1;
        for (int i = tid; i < 1600; i += 256) {
            uint32_t o0, o1;
            threefry2x32(k20, k21, (uint32_t)i, (uint32_t)(1600 + i), o0, o1);
            samp[l * 3200 + i]        = (int)(o0 & 127u);
            samp[l * 3200 + 1600 + i] = (int)(o1 & 127u);
        }
    }
}

// ---------------- patch embedding + sinusoidal PE (fp32 + bf16 out) ----------------
__global__ void patch_embed(const float* __restrict__ x, const float* __restrict__ pw,
                            const float* __restrict__ mean, const float* __restrict__ stdv,
                            float* __restrict__ tok, short* __restrict__ tokb) {
    int p = blockIdx.x, bc = blockIdx.y;
    int b = bc / CIN, c = bc % CIN;
    __shared__ float xs[16];
    if (threadIdx.x < 16) {
        int i = p * 8 + threadIdx.x;
        if (i > SEQ - 1) i = SEQ - 1;   // edge pad
        xs[threadIdx.x] = (x[(size_t)b * SEQ * CIN + (size_t)i * CIN + c] - mean[bc]) / stdv[bc];
    }
    __syncthreads();
    for (int d = threadIdx.x; d < DM; d += blockDim.x) {
        float acc = 0.f;
        const float* wr = pw + d * 16;
        #pragma unroll
        for (int t = 0; t < 16; t++) acc += xs[t] * wr[t];
        int k2 = d & ~1;
        float ang = (float)p * __expf((float)k2 * PE_COEF);
        acc += (d & 1) ? __cosf(ang) : __sinf(ang);
        size_t idx = ((size_t)bc * NP + p) * DM + d;
        tok[idx] = acc;
        tokb[idx] = f2bf(acc);
    }
}

// ---------------- MFMA GEMM 128x128, 2-phase double-buffered pipeline ----------------
template<int ACT, int OBF>   // ACT: 0 none, 1 fast GELU; OBF: 0 fp32 out, 1 bf16 out
__global__ __launch_bounds__(256) void gemm_mfma(const short* __restrict__ A,
                                                 const short* __restrict__ W,
                                                 const float* __restrict__ bias,
                                                 float* __restrict__ Cf,
                                                 short* __restrict__ Cb,
                                                 int M, int N, int K) {
    __shared__ short LDSU[2][16384];   // [buf][ A:0..8191 | B:8192..16383 ]  64 KB
    int tid = threadIdx.x;
    int w = tid >> 6, lane = tid & 63;
    int row0 = blockIdx.x * 128, col0 = blockIdx.y * 128;
    int wrow = (w >> 1) * 64, wcol = (w & 1) * 64;
    int nt = K >> 6;
    f32x4 acc[4][4] = {};

    auto stage = [&](int b, int kt) {
        #pragma unroll
        for (int i = 0; i < 4; i++) {
            int L = i * 4096 + w * 1024 + lane * 16;    // linear LDS byte offset
            int row = L >> 7;
            int cb  = L & 127;
            int scb = cb ^ ((row & 7) << 4);             // inverse-swizzled source col
            gl_lds16(A + (size_t)(row0 + row) * K + kt + (scb >> 1),
                     (char*)&LDSU[b][0] + i * 4096 + w * 1024);
            gl_lds16(W + (size_t)(col0 + row) * K + kt + (scb >> 1),
                     (char*)&LDSU[b][8192] + i * 4096 + w * 1024);
        }
    };

    stage(0, 0);
    __syncthreads();
    int cur = 0;
    for (int t = 0; t < nt; t++) {
        if (t + 1 < nt) stage(cur ^ 1, (t + 1) * 64);   // prefetch under compute
        const char* Ab = (const char*)&LDSU[cur][0];
        const char* Bb = (const char*)&LDSU[cur][8192];
        #pragma unroll
        for (int ks = 0; ks < 2; ks++) {
            int cb = ks * 64 + ((lane >> 4) << 4);
            short8 af[4], bfr[4];
            #pragma unroll
            for (int m = 0; m < 4; m++) {
                int r = wrow + m * 16 + (lane & 15);
                af[m] = *(const short8*)(Ab + r * 128 + (cb ^ ((r & 7) << 4)));
            }
            #pragma unroll
            for (int n = 0; n < 4; n++) {
                int r = wcol + n * 16 + (lane & 15);
                bfr[n] = *(const short8*)(Bb + r * 128 + (cb ^ ((r & 7) << 4)));
            }
            #pragma unroll
            for (int m = 0; m < 4; m++)
                #pragma unroll
                for (int n = 0; n < 4; n++)
                    acc[m][n] = __builtin_amdgcn_mfma_f32_16x16x32_bf16(af[m], bfr[n], acc[m][n], 0, 0, 0);
        }
        __syncthreads();
        cur ^= 1;
    }

    #pragma unroll
    for (int m = 0; m < 4; m++) {
        int rbase = row0 + wrow + m * 16 + ((lane >> 4) << 2);
        #pragma unroll
        for (int n = 0; n < 4; n++) {
            int col = col0 + wcol + n * 16 + (lane & 15);
            float bval = bias[col];
            #pragma unroll
            for (int j = 0; j < 4; j++) {
                float v = acc[m][n][j] + bval;
                if (ACT == 1) {
                    float u = 0.7978845608f * (v + 0.044715f * v * v * v);
                    float e = exp2f(2.8853900817779268f * u);
                    v = v - v / (e + 1.0f);
                }
                if (OBF) Cb[(size_t)(rbase + j) * N + col] = f2bf(v);
                else     Cf[(size_t)(rbase + j) * N + col] = v;
            }
        }
    }
}

// ---------------- fused GEMM (N=512 full-row) + residual + LayerNorm (+ optional 2nd LN) ----
// 32-row tile, 4 waves x 128 cols; A via LDS double-buffer; W fragments direct from L2.
template<int SECOND_LN>
__global__ __launch_bounds__(256) void gemm_ln(const short* __restrict__ A,
                                               const short* __restrict__ W,
                                               const float* __restrict__ bias,
                                               const float* __restrict__ resid,
                                               const float* __restrict__ g,
                                               const float* __restrict__ beta,
                                               const float* __restrict__ g2,
                                               const float* __restrict__ beta2,
                                               float* __restrict__ outF,
                                               short* __restrict__ outB,
                                               int K) {
    __shared__ short Als[2][2048];    // 2 x 4 KB, XOR-swizzled rows of 128 B
    __shared__ float lsum[4][32];
    __shared__ float lssq[4][32];
    int tid = threadIdx.x, w = tid >> 6, lane = tid & 63;
    int cl = lane & 15, lg = lane >> 4;
    int row0 = blockIdx.x * 32;
    int nt = K >> 6;
    f32x4 acc[2][8] = {};

    auto stageA = [&](int b, int kt) {
        int L = tid * 16;
        int row = L >> 7, cb = L & 127;
        int scb = cb ^ ((row & 7) << 4);
        gl_lds16(A + (size_t)(row0 + row) * K + kt + (scb >> 1),
                 (char*)&Als[b][0] + w * 1024 + lane * 16);
    };

    stageA(0, 0);
    __syncthreads();
    int cur = 0;
    for (int t = 0; t < nt; t++) {
        if (t + 1 < nt) stageA(cur ^ 1, (t + 1) * 64);
        const char* Ab = (const char*)&Als[cur][0];
        int kt = t * 64;
        #pragma unroll
        for (int ks = 0; ks < 2; ks++) {
            int cb = ks * 64 + (lg << 4);
            short8 af0, af1;
            {
                int r = cl;
                af0 = *(const short8*)(Ab + r * 128 + (cb ^ ((r & 7) << 4)));
                r = 16 + cl;
                af1 = *(const short8*)(Ab + r * 128 + (cb ^ ((r & 7) << 4)));
            }
            #pragma unroll
            for (int n = 0; n < 8; n++) {
                int col = w * 128 + n * 16 + cl;
                short8 bf = *(const short8*)(W + (size_t)col * K + kt + ks * 32 + lg * 8);
                acc[0][n] = __builtin_amdgcn_mfma_f32_16x16x32_bf16(af0, bf, acc[0][n], 0, 0, 0);
                acc[1][n] = __builtin_amdgcn_mfma_f32_16x16x32_bf16(af1, bf, acc[1][n], 0, 0, 0);
            }
        }
        __syncthreads();
        cur ^= 1;
    }

    int colb = w * 128 + cl;
    float gv[8], bev[8];
    #pragma unroll
    for (int n = 0; n < 8; n++) {
        int c = colb + n * 16;
        float bb = bias[c];
        gv[n] = g[c]; bev[n] = beta[c];
        #pragma unroll
        for (int m = 0; m < 2; m++)
            #pragma unroll
            for (int j = 0; j < 4; j++)
                acc[m][n][j] += bb + resid[(size_t)(row0 + m * 16 + lg * 4 + j) * DM + c];
    }

    // LN pass 1: row sums via 16-lane shuffle + cross-wave LDS
    #pragma unroll
    for (int m = 0; m < 2; m++)
        #pragma unroll
        for (int j = 0; j < 4; j++) {
            float s = 0.f, ss = 0.f;
            #pragma unroll
            for (int n = 0; n < 8; n++) { float t = acc[m][n][j]; s += t; ss += t * t; }
            #pragma unroll
            for (int mk = 1; mk <= 8; mk <<= 1) { s += __shfl_xor(s, mk); ss += __shfl_xor(ss, mk); }
            if (cl == 0) { lsum[w][m * 16 + lg * 4 + j] = s; lssq[w][m * 16 + lg * 4 + j] = ss; }
        }
    __syncthreads();
    #pragma unroll
    for (int m = 0; m < 2; m++)
        #pragma unroll
        for (int j = 0; j < 4; j++) {
            int r = m * 16 + lg * 4 + j;
            float s  = lsum[0][r] + lsum[1][r] + lsum[2][r] + lsum[3][r];
            float ss = lssq[0][r] + lssq[1][r] + lssq[2][r] + lssq[3][r];
            float mu = s * (1.0f / DM);
            float var = ss * (1.0f / DM) - mu * mu;
            float rstd = rsqrtf(var + 1e-5f);
            #pragma unroll
            for (int n = 0; n < 8; n++)
                acc[m][n][j] = (acc[m][n][j] - mu) * rstd * gv[n] + bev[n];
        }

    if (SECOND_LN) {
        #pragma unroll
        for (int n = 0; n < 8; n++) { int c = colb + n * 16; gv[n] = g2[c]; bev[n] = beta2[c]; }
        __syncthreads();   // everyone done reading pass-1 lsum
        #pragma unroll
        for (int m = 0; m < 2; m++)
            #pragma unroll
            for (int j = 0; j < 4; j++) {
                float s = 0.f, ss = 0.f;
                #pragma unroll
                for (int n = 0; n < 8; n++) { float t = acc[m][n][j]; s += t; ss += t * t; }
                #pragma unroll
                for (int mk = 1; mk <= 8; mk <<= 1) { s += __shfl_xor(s, mk); ss += __shfl_xor(ss, mk); }
                if (cl == 0) { lsum[w][m * 16 + lg * 4 + j] = s; lssq[w][m * 16 + lg * 4 + j] = ss; }
            }
        __syncthreads();
        #pragma unroll
        for (int m = 0; m < 2; m++)
            #pragma unroll
            for (int j = 0; j < 4; j++) {
                int r = m * 16 + lg * 4 + j;
                float s  = lsum[0][r] + lsum[1][r] + lsum[2][r] + lsum[3][r];
                float ss = lssq[0][r] + lssq[1][r] + lssq[2][r] + lssq[3][r];
                float mu = s * (1.0f / DM);
                float var = ss * (1.0f / DM) - mu * mu;
                float rstd = rsqrtf(var + 1e-5f);
                #pragma unroll
                for (int n = 0; n < 8; n++)
                    acc[m][n][j] = (acc[m][n][j] - mu) * rstd * gv[n] + bev[n];
            }
    }

    #pragma unroll
    for (int m = 0; m < 2; m++)
        #pragma unroll
        for (int j = 0; j < 4; j++) {
            size_t row = row0 + m * 16 + lg * 4 + j;
            #pragma unroll
            for (int n = 0; n < 8; n++) {
                float v = acc[m][n][j];
                outF[row * DM + colb + n * 16] = v;
                if (outB) outB[row * DM + colb + n * 16] = f2bf(v);
            }
        }
}

// ---------------- fused ProbSparse attention (one block per (bc,h)) ----------------
__global__ __launch_bounds__(256, 2) void attn_fused(const short* __restrict__ qkvb,
                                                     const int* __restrict__ samp,
                                                     short* __restrict__ ctxb) {
    __shared__ float Sbuf[64 * 130];   // 33.28 KB; overlays Stop[32*130] + Pb
    __shared__ short Vt[64 * 128];     // 16 KB, XOR-swizzled rows of 256 B
    __shared__ short Kls[128 * 64];    // 16 KB, XOR-swizzled rows of 128 B
    __shared__ float Mv[128];
    __shared__ int   topl[32];
    __shared__ float vmean[64];
    __shared__ float vpart[256];

    float* Stop = Sbuf;                          // 32 x 130 fp32
    short* Pb   = (short*)(Sbuf + 32 * 130);     // 32 x 128 bf16, XOR-swizzled

    int bh = blockIdx.x, bc = bh >> 3, h = bh & 7;
    int tid = threadIdx.x, w = tid >> 6, lane = tid & 63;
    const short* base = qkvb + (size_t)bc * NP * 1536 + h * DH;
    short* cbase = ctxb + (size_t)bc * NP * DM + h * DH;

    // P0: stage K (swizzled rows) + V transposed (swizzled)
    for (int e = tid; e < 1024; e += 256) {
        int row = e >> 3, c8 = e & 7;
        short8 kv = *(const short8*)(base + (size_t)row * 1536 + 512 + c8 * 8);
        *(short8*)((char*)Kls + row * 128 + ((c8 * 16) ^ ((row & 7) << 4))) = kv;
        short8 vv = *(const short8*)(base + (size_t)row * 1536 + 1024 + c8 * 8);
        #pragma unroll
        for (int j = 0; j < 8; j++) {
            int d = c8 * 8 + j;
            *(short*)((char*)Vt + d * 256 + ((2 * row) ^ ((d & 7) << 4))) = vv[j];
        }
    }
    __syncthreads();
    {
        int d = tid & 63, part = tid >> 6;
        float s = 0.f;
        #pragma unroll
        for (int i4 = 0; i4 < 4; i4++) {
            short8 v = *(const short8*)((char*)Vt + d * 256 + ((part * 64 + i4 * 16) ^ ((d & 7) << 4)));
            #pragma unroll
            for (int j = 0; j < 8; j++) s += bf2f(v[j]);
        }
        vpart[part * 64 + d] = s;
    }

    // P2: S halves (64 rows each) + M-score gather per half
    for (int half = 0; half < 2; half++) {
        int ar = half * 64 + 16 * w + (lane & 15);
        const short* qp = base + (size_t)ar * 1536;
        short8 a0 = *(const short8*)(qp + (lane >> 4) * 8);
        short8 a1 = *(const short8*)(qp + 32 + (lane >> 4) * 8);
        #pragma unroll 2
        for (int ct = 0; ct < 8; ct++) {
            int br = ct * 16 + (lane & 15);
            int cb0 = (lane >> 4) * 16;
            short8 b0 = *(const short8*)((char*)Kls + br * 128 + (cb0 ^ ((br & 7) << 4)));
            short8 b1 = *(const short8*)((char*)Kls + br * 128 + ((cb0 + 64) ^ ((br & 7) << 4)));
            f32x4 acc = {};
            acc = __builtin_amdgcn_mfma_f32_16x16x32_bf16(a0, b0, acc, 0, 0, 0);
            acc = __builtin_amdgcn_mfma_f32_16x16x32_bf16(a1, b1, acc, 0, 0, 0);
            int r0 = 16 * w + ((lane >> 4) << 2);
            int c = ct * 16 + (lane & 15);
            #pragma unroll
            for (int j = 0; j < 4; j++) Sbuf[(r0 + j) * 130 + c] = acc[j] * 0.125f;
        }
        __syncthreads();
        if (tid < 64) {
            int r = half * 64 + tid;
            const int* sp = samp + r * U;
            const float* Srow = &Sbuf[tid * 130];
            float mx = -1e30f, sm = 0.f;
            #pragma unroll
            for (int s = 0; s < U; s++) { float v = Srow[sp[s]]; mx = fmaxf(mx, v); sm += v; }
            Mv[r] = mx - sm * (1.0f / U);
        } else if (half == 0 && tid < 128) {
            int d = tid - 64;
            vmean[d] = (vpart[d] + vpart[64 + d] + vpart[128 + d] + vpart[192 + d]) * (1.0f / 128.0f);
        }
        __syncthreads();
    }

    // P6: wave0 = top-25 shuffle argmax; waves 1-3 = broadcast vmean to ALL ctx rows
    if (w == 0) {
        float v0 = Mv[lane], v1 = Mv[lane + 64];
        for (int it = 0; it < U; it++) {
            float bv; int bi;
            if (v1 > v0) { bv = v1; bi = lane + 64; } else { bv = v0; bi = lane; }
            #pragma unroll
            for (int o = 32; o > 0; o >>= 1) {
                float ov = __shfl_xor(bv, o);
                int   oi = __shfl_xor(bi, o);
                if (ov > bv || (ov == bv && oi < bi)) { bv = ov; bi = oi; }
            }
            if (lane == 0) topl[it] = bi;
            if (bi == lane) v0 = -1e30f;
            if (bi == lane + 64) v1 = -1e30f;
        }
    } else {
        for (int e = tid - 64; e < 128 * 16; e += 192) {
            int n = e >> 4, c4 = e & 15;
            short4 o;
            o.x = f2bf(vmean[c4 * 4 + 0]); o.y = f2bf(vmean[c4 * 4 + 1]);
            o.z = f2bf(vmean[c4 * 4 + 2]); o.w = f2bf(vmean[c4 * 4 + 3]);
            *(short4*)(cbase + (size_t)n * DM + c4 * 4) = o;
        }
    }
    __syncthreads();

    // P7: recompute scores for the 25 top rows into Stop
    {
        int rt = w & 1, cth = w >> 1;
        int u = rt * 16 + (lane & 15);
        int qrow = topl[u < U ? u : U - 1];
        const short* qp = base + (size_t)qrow * 1536;
        short8 a0 = *(const short8*)(qp + (lane >> 4) * 8);
        short8 a1 = *(const short8*)(qp + 32 + (lane >> 4) * 8);
        #pragma unroll
        for (int cti = 0; cti < 4; cti++) {
            int ct = cth * 4 + cti;
            int br = ct * 16 + (lane & 15);
            int cb0 = (lane >> 4) * 16;
            short8 b0 = *(const short8*)((char*)Kls + br * 128 + (cb0 ^ ((br & 7) << 4)));
            short8 b1 = *(const short8*)((char*)Kls + br * 128 + ((cb0 + 64) ^ ((br & 7) << 4)));
            f32x4 acc = {};
            acc = __builtin_amdgcn_mfma_f32_16x16x32_bf16(a0, b0, acc, 0, 0, 0);
            acc = __builtin_amdgcn_mfma_f32_16x16x32_bf16(a1, b1, acc, 0, 0, 0);
            int r0 = rt * 16 + ((lane >> 4) << 2);
            int c = ct * 16 + (lane & 15);
            #pragma unroll
            for (int j = 0; j < 4; j++) Stop[(r0 + j) * 130 + c] = acc[j] * 0.125f;
        }
    }
    __syncthreads();

    // P8: softmax of top rows -> Pb (bf16, swizzled); zero pad rows 25..31
    for (int e = tid; e < 7 * 128; e += 256)
        Pb[(25 + (e >> 7)) * 128 + (e & 127)] = 0;
    for (int it = w; it < U; it += 4) {
        float s0 = Stop[it * 130 + lane], s1 = Stop[it * 130 + 64 + lane];
        float mx = fmaxf(s0, s1);
        #pragma unroll
        for (int o = 32; o > 0; o >>= 1) mx = fmaxf(mx, __shfl_xor(mx, o));
        float e0 = expf(s0 - mx), e1 = expf(s1 - mx);
        float sum = e0 + e1;
        #pragma unroll
        for (int o = 32; o > 0; o >>= 1) sum += __shfl_xor(sum, o);
        float inv = 1.0f / sum;
        int sw = (it & 7) << 4;
        *(short*)((char*)Pb + it * 256 + ((2 * lane) ^ sw))        = f2bf(e0 * inv);
        *(short*)((char*)Pb + it * 256 + ((2 * (64 + lane)) ^ sw)) = f2bf(e1 * inv);
    }
    __syncthreads();

    // P9: PV via MFMA, scatter to top rows
    #pragma unroll
    for (int t = w * 2; t < w * 2 + 2; t++) {
        int rt = t >> 2, ct = t & 3;
        int pr = rt * 16 + (lane & 15);
        int vr = ct * 16 + (lane & 15);
        f32x4 acc = {};
        #pragma unroll
        for (int ks = 0; ks < 4; ks++) {
            int off = ks * 64 + (lane >> 4) * 16;
            short8 a = *(const short8*)((char*)Pb + pr * 256 + (off ^ ((pr & 7) << 4)));
            short8 b = *(const short8*)((char*)Vt + vr * 256 + (off ^ ((vr & 7) << 4)));
            acc = __builtin_amdgcn_mfma_f32_16x16x32_bf16(a, b, acc, 0, 0, 0);
        }
        int u0 = rt * 16 + ((lane >> 4) << 2), d = ct * 16 + (lane & 15);
        #pragma unroll
        for (int j = 0; j < 4; j++) {
            int u = u0 + j;
            if (u < U) cbase[(size_t)topl[u] * DM + d] = f2bf(acc[j]);
        }
    }
}

// ---------------- transpose tok(bc,p,d) fp32 -> featb(bc,d,p) bf16 ----------------
__global__ void transpose_tok(const float* __restrict__ tok, short* __restrict__ featb) {
    __shared__ float t[32][33];
    int bc = blockIdx.z, dt = blockIdx.y, pt = blockIdx.x;
    int tx = threadIdx.x, ty = threadIdx.y;
    #pragma unroll
    for (int i = 0; i < 4; i++) {
        int p = pt * 32 + ty + i * 8;
        int d = dt * 32 + tx;
        t[ty + i * 8][tx] = tok[((size_t)bc * NP + p) * DM + d];
    }
    __syncthreads();
    #pragma unroll
    for (int i = 0; i < 4; i++) {
        int d = dt * 32 + ty + i * 8;
        int p = pt * 32 + tx;
        featb[(size_t)bc * (DM * NP) + (size_t)d * NP + p] = f2bf(t[tx][ty + i * 8]);
    }
}

// ---------------- head MFMA split-K: partial[blk][96][64] ----------------
__global__ __launch_bounds__(256) void head_mfma(const float* __restrict__ hw,
                                                 const short* __restrict__ featb,
                                                 float* __restrict__ partial) {
    __shared__ short Als[96 * 64];
    __shared__ short Bls[64 * 64];
    int tid = threadIdx.x;
    int w = tid >> 6, lane = tid & 63;
    int wm = w >> 1, wn = w & 1;
    int kb = blockIdx.x * HKB;
    f32x4 acc[3][2] = {};
    const char* Ab = (const char*)Als;
    const char* Bb = (const char*)Bls;

    for (int kt = 0; kt < HKB; kt += 64) {
        #pragma unroll
        for (int i = 0; i < 6; i++) {
            int s = tid + i * 256;
            int row = s >> 4, c4 = s & 15;
            float4 v = *(const float4*)(hw + (size_t)row * 65536 + kb + kt + c4 * 4);
            short4 o; o.x = f2bf(v.x); o.y = f2bf(v.y); o.z = f2bf(v.z); o.w = f2bf(v.w);
            int boff = row * 128 + ((c4 * 8) ^ ((row & 7) << 4));
            *(short4*)((char*)Als + boff) = o;
        }
        #pragma unroll
        for (int i = 0; i < 4; i++) {
            int s = tid + i * 256;
            int row = s >> 4, c4 = s & 15;
            short4 o;
            if (row < BC) o = *(const short4*)(featb + (size_t)row * 65536 + kb + kt + c4 * 4);
            else { o.x = 0; o.y = 0; o.z = 0; o.w = 0; }
            int boff = row * 128 + ((c4 * 8) ^ ((row & 7) << 4));
            *(short4*)((char*)Bls + boff) = o;
        }
        __syncthreads();
        #pragma unroll
        for (int ks = 0; ks < 2; ks++) {
            int cb = ks * 64 + ((lane >> 4) << 4);
            short8 af[3], bfr[2];
            #pragma unroll
            for (int m = 0; m < 3; m++) {
                int r = wm * 48 + m * 16 + (lane & 15);
                af[m] = *(const short8*)(Ab + r * 128 + (cb ^ ((r & 7) << 4)));
            }
            #pragma unroll
            for (int n = 0; n < 2; n++) {
                int r = wn * 32 + n * 16 + (lane & 15);
                bfr[n] = *(const short8*)(Bb + r * 128 + (cb ^ ((r & 7) << 4)));
            }
            #pragma unroll
            for (int m = 0; m < 3; m++)
                #pragma unroll
                for (int n = 0; n < 2; n++)
                    acc[m][n] = __builtin_amdgcn_mfma_f32_16x16x32_bf16(af[m], bfr[n], acc[m][n], 0, 0, 0);
        }
        __syncthreads();
    }

    float* pb = partial + (size_t)blockIdx.x * (96 * 64);
    #pragma unroll
    for (int m = 0; m < 3; m++) {
        int rbase = wm * 48 + m * 16 + ((lane >> 4) << 2);
        #pragma unroll
        for (int n = 0; n < 2; n++) {
            int col = wn * 32 + n * 16 + (lane & 15);
            #pragma unroll
            for (int j = 0; j < 4; j++)
                pb[(rbase + j) * 64 + col] = acc[m][n][j];
        }
    }
}

// ---------------- finalize: 2-stage split-K reduction + bias + de-norm ----------------
__global__ void finalize_a(const float* __restrict__ partial, float* __restrict__ p2) {
    int i = blockIdx.x * 256 + threadIdx.x;   // 0..6143
    int s = blockIdx.y;                        // 0..7
    const float* p = partial + (size_t)s * 32 * 6144 + i;
    float sum = 0.f;
    #pragma unroll
    for (int b = 0; b < 32; b++) sum += p[(size_t)b * 6144];
    p2[s * 6144 + i] = sum;
}

__global__ void finalize_b(const float* __restrict__ p2, const float* __restrict__ hb,
                           const float* __restrict__ mean, const float* __restrict__ stdv,
                           float* __restrict__ out) {
    int i = blockIdx.x * 256 + threadIdx.x;
    if (i >= NB * 96 * CIN) return;
    int b = i / (96 * CIN);
    int r = i % (96 * CIN);
    int t = r / CIN, c = r % CIN;
    int bc = b * CIN + c;
    int j = t * 64 + bc;
    float s = 0.f;
    #pragma unroll
    for (int k = 0; k < 8; k++) s += p2[k * 6144 + j];
    out[i] = (s + hb[t]) * stdv[bc] + mean[bc];
}

// ---------------- launch ----------------
extern "C" void kernel_launch(void* const* d_in, const int* in_sizes, int n_in,
                              void* d_out, int out_size, void* d_ws, size_t ws_size,
                              hipStream_t stream) {
    (void)in_sizes; (void)n_in; (void)out_size; (void)ws_size;
    const float* x_enc   = (const float*)d_in[0];
    const float* patch_W = (const float*)d_in[4];
    const float* Wq  = (const float*)d_in[5];
    const float* bq  = (const float*)d_in[6];
    const float* Wk  = (const float*)d_in[7];
    const float* bk  = (const float*)d_in[8];
    const float* Wv  = (const float*)d_in[9];
    const float* bv  = (const float*)d_in[10];
    const float* Wo  = (const float*)d_in[11];
    const float* bo  = (const float*)d_in[12];
    const float* c1W = (const float*)d_in[13];
    const float* c1b = (const float*)d_in[14];
    const float* c2W = (const float*)d_in[15];
    const float* c2b = (const float*)d_in[16];
    const float* ln1g = (const float*)d_in[17];
    const float* ln1b = (const float*)d_in[18];
    const float* ln2g = (const float*)d_in[19];
    const float* ln2b = (const float*)d_in[20];
    const float* encg = (const float*)d_in[21];
    const float* encb = (const float*)d_in[22];
    const float* headW = (const float*)d_in[23];
    const float* headb = (const float*)d_in[24];
    float* out = (float*)d_out;

    float* ws = (float*)d_ws;
    float* mean = ws + 0;
    float* stdv = ws + 64;
    float* bqkv = ws + 128;                 // 2*1536 floats
    int*   samp = (int*)(ws + 6144);        // 6400 ints
    size_t off = 32768;
    const size_t T = (size_t)NTOK * DM;     // 3,670,016
    float* tok     = ws + off; off += T;
    float* x1      = ws + off; off += T;      // also reused as p2 in head phase
    float* partial = ws + off; off += T;      // head split-K partials (256*6144)
    float* p2      = x1;
    // bf16 region
    short* sbase = (short*)(ws + off);
    size_t soff = 0;
    short* tok_b  = sbase + soff; soff += T;
    short* ctx_b  = sbase + soff; soff += T;
    short* x1_b   = sbase + soff; soff += T;
    short* qkv_b  = sbase + soff; soff += 3 * T;            // bf16 QKV
    short* ffn_b  = sbase + soff; soff += (size_t)NTOK * DFF;
    short* featb  = ffn_b;                  // reuse: ffn_b dead after encoder loop
    short* wqkv_b = sbase + soff; soff += 2 * 1536 * DM;
    short* wo_b   = sbase + soff; soff += 2 * DM * DM;
    short* c1w_b  = sbase + soff; soff += 2 * (size_t)DFF * DM;
    short* c2w_b  = sbase + soff; soff += 2 * (size_t)DM * DFF;

    stats_kernel<<<BC, 256, 0, stream>>>(x_enc, mean, stdv);
    prep_weights<<<6146, 256, 0, stream>>>(Wq, Wk, Wv, bq, bk, bv, Wo, c1W, c2W,
                                           wqkv_b, bqkv, wo_b, c1w_b, c2w_b, samp);
    patch_embed<<<dim3(NP, BC), 128, 0, stream>>>(x_enc, patch_W, mean, stdv, tok, tok_b);

    for (int l = 0; l < 2; l++) {
        // QKV (bf16 out)
        gemm_mfma<0,1><<<dim3(56, 12), 256, 0, stream>>>(tok_b, wqkv_b + (size_t)l * 1536 * DM, bqkv + l * 1536, nullptr, qkv_b, NTOK, 1536, DM);
        attn_fused<<<448, 256, 0, stream>>>(qkv_b, samp + l * 3200, ctx_b);
        // Wo + residual(tok) + LN1 -> x1 (fp32) + x1_b (bf16)
        gemm_ln<0><<<224, 256, 0, stream>>>(ctx_b, wo_b + (size_t)l * DM * DM, bo + l * DM,
                                            tok, ln1g + l * DM, ln1b + l * DM,
                                            nullptr, nullptr, x1, x1_b, DM);
        // FFN1 (fast GELU, bf16 out)
        gemm_mfma<1,1><<<dim3(56, 16), 256, 0, stream>>>(x1_b, c1w_b + (size_t)l * DFF * DM, c1b + l * DFF, nullptr, ffn_b, NTOK, DFF, DM);
        // FFN2 + residual(x1) + LN2 (+ final enc LN on last layer)
        if (l == 0)
            gemm_ln<0><<<224, 256, 0, stream>>>(ffn_b, c2w_b + (size_t)l * DM * DFF, c2b + l * DM,
                                                x1, ln2g + l * DM, ln2b + l * DM,
                                                nullptr, nullptr, tok, tok_b, DFF);
        else
            gemm_ln<1><<<224, 256, 0, stream>>>(ffn_b, c2w_b + (size_t)l * DM * DFF, c2b + l * DM,
                                                x1, ln2g + l * DM, ln2b + l * DM,
                                                encg, encb, tok, nullptr, DFF);
    }

    transpose_tok<<<dim3(4, 16, BC), dim3(32, 8), 0, stream>>>(tok, featb);
    head_mfma<<<HNB, 256, 0, stream>>>(headW, featb, partial);
    finalize_a<<<dim3(24, 8), 256, 0, stream>>>(partial, p2);
    finalize_b<<<21, 256, 0, stream>>>(p2, headb, mean, stdv, out);
}

// Round 10
// 321.310 us; speedup vs baseline: 1.3176x; 1.3176x over previous
//
#include <hip/hip_runtime.h>
#include <math.h>
#include <stdint.h>

#define SEQ   1024
#define CIN   7
#define NB    8
#define BC    56          // NB*CIN
#define NP    128         // patches
#define DM    512
#define NH    8
#define DH    64
#define DFF   2048
#define U     25
#define NTOK  (BC*NP)     // 7168
#define PE_COEF (-9.210340371976184f / 512.0f)  // -ln(10000)/DM
#define HKB   256         // head: K elems per split-K block
#define HNB   256         // head: number of split-K blocks (HKB*HNB = 65536)

typedef __attribute__((ext_vector_type(8))) short short8;
typedef __attribute__((ext_vector_type(4))) float f32x4;

__device__ __forceinline__ short f2bf(float x) {
    union { float f; uint32_t u; } v; v.f = x;
    uint32_t r = v.u + 0x7FFFu + ((v.u >> 16) & 1u);
    return (short)(r >> 16);
}
__device__ __forceinline__ float bf2f(short x) {
    union { uint32_t u; float f; } v; v.u = ((uint32_t)(uint16_t)x) << 16;
    return v.f;
}

__device__ __forceinline__ void gl_lds16(const void* g, void* s) {
    __builtin_amdgcn_global_load_lds((const __attribute__((address_space(1))) void*)g,
                                     (__attribute__((address_space(3))) void*)s, 16, 0, 0);
}

// ---------------- stats: per (b,c) mean/std over SEQ ----------------
__global__ void stats_kernel(const float* __restrict__ x, float* __restrict__ mean,
                             float* __restrict__ stdv) {
    int bc = blockIdx.x; int b = bc / CIN, c = bc % CIN;
    const float* base = x + (size_t)b * SEQ * CIN + c;
    float s = 0.f, ss = 0.f;
    for (int i = threadIdx.x; i < SEQ; i += 256) {
        float v = base[(size_t)i * CIN];
        s += v; ss += v * v;
    }
    __shared__ float rs[256], rss[256];
    rs[threadIdx.x] = s; rss[threadIdx.x] = ss; __syncthreads();
    for (int o = 128; o > 0; o >>= 1) {
        if (threadIdx.x < o) { rs[threadIdx.x] += rs[threadIdx.x + o]; rss[threadIdx.x] += rss[threadIdx.x + o]; }
        __syncthreads();
    }
    if (threadIdx.x == 0) {
        float m = rs[0] / SEQ;
        float v = rss[0] / SEQ - m * m;
        mean[bc] = m;
        stdv[bc] = sqrtf(v + 1e-5f);
    }
}

// ---------------- threefry2x32-20 (JAX PRNG) ----------------
__device__ __forceinline__ void tf_round(uint32_t& x0, uint32_t& x1, uint32_t r) {
    x0 += x1; x1 = (x1 << r) | (x1 >> (32u - r)); x1 ^= x0;
}
__device__ void threefry2x32(uint32_t k0, uint32_t k1, uint32_t x0, uint32_t x1,
                             uint32_t& o0, uint32_t& o1) {
    uint32_t ks[3] = { k0, k1, k0 ^ k1 ^ 0x1BD11BDAu };
    x0 += ks[0]; x1 += ks[1];
    const uint32_t rotA[4] = {13u, 15u, 26u, 6u}, rotB[4] = {17u, 29u, 16u, 24u};
    #pragma unroll
    for (int i = 0; i < 5; i++) {
        const uint32_t* rr = (i & 1) ? rotB : rotA;
        tf_round(x0, x1, rr[0]); tf_round(x0, x1, rr[1]);
        tf_round(x0, x1, rr[2]); tf_round(x0, x1, rr[3]);
        x0 += ks[(i + 1) % 3];
        x1 += ks[(i + 2) % 3] + (uint32_t)(i + 1);
    }
    o0 = x0; o1 = x1;
}

// ---------------- fused prep: pack QKV weights, convert Wo/c1W/c2W, samp ----------------
__global__ void prep_weights(const float* __restrict__ Wq, const float* __restrict__ Wk,
                             const float* __restrict__ Wv, const float* __restrict__ bq,
                             const float* __restrict__ bk, const float* __restrict__ bv,
                             const float* __restrict__ Wo, const float* __restrict__ c1W,
                             const float* __restrict__ c2W,
                             short* __restrict__ wqkv, float* __restrict__ bqkv,
                             short* __restrict__ wo_b, short* __restrict__ c1w_b,
                             short* __restrict__ c2w_b, int* __restrict__ samp) {
    int blk = blockIdx.x, tid = threadIdx.x;
    if (blk < 1536) {                       // pack_qkv: 2*1536*128 float4 slots
        int idx = blk * 256 + tid;
        int k4 = idx & 127;
        int n  = (idx >> 7) % 1536;
        int l  = idx / (1536 * 128);
        int sel3 = n >> 9;
        int nn = n & 511;
        const float* src = sel3 == 0 ? Wq : sel3 == 1 ? Wk : Wv;
        float4 v = *(const float4*)(src + ((size_t)l * DM + nn) * DM + k4 * 4);
        short4 o; o.x = f2bf(v.x); o.y = f2bf(v.y); o.z = f2bf(v.z); o.w = f2bf(v.w);
        *(short4*)(wqkv + ((size_t)l * 1536 + n) * DM + k4 * 4) = o;
        if (k4 == 0) {
            const float* bsrc = sel3 == 0 ? bq : sel3 == 1 ? bk : bv;
            bqkv[l * 1536 + n] = bsrc[l * DM + nn];
        }
    } else if (blk < 6144) {                // converts
        const float* in; short* out; int i;
        if (blk < 2048)      { in = Wo;  out = wo_b;  i = (blk - 1536) * 256 + tid; }
        else if (blk < 4096) { in = c1W; out = c1w_b; i = (blk - 2048) * 256 + tid; }
        else                 { in = c2W; out = c2w_b; i = (blk - 4096) * 256 + tid; }
        float4 v = ((const float4*)in)[i];
        short4 o; o.x = f2bf(v.x); o.y = f2bf(v.y); o.z = f2bf(v.z); o.w = f2bf(v.w);
        ((short4*)out)[i] = o;
    } else {                                 // samp: 2 blocks
        int l = blk - 6144;
        uint32_t s0, s1; threefry2x32(0u, 42u, 0u, (uint32_t)l, s0, s1);
        uint32_t a0, a1, b0, b1;
        threefry2x32(s0, s1, 0u, 2u, a0, a1);
        threefry2x32(s0, s1, 1u, 3u, b0, b1);
        uint32_t k20 = a1, k21 = b1;
        for (int i = tid; i < 1600; i += 256) {
            uint32_t o0, o1;
            threefry2x32(k20, k21, (uint32_t)i, (uint32_t)(1600 + i), o0, o1);
            samp[l * 3200 + i]        = (int)(o0 & 127u);
            samp[l * 3200 + 1600 + i] = (int)(o1 & 127u);
        }
    }
}

// ---------------- patch embedding + sinusoidal PE (fp32 + bf16 out) ----------------
__global__ void patch_embed(const float* __restrict__ x, const float* __restrict__ pw,
                            const float* __restrict__ mean, const float* __restrict__ stdv,
                            float* __restrict__ tok, short* __restrict__ tokb) {
    int p = blockIdx.x, bc = blockIdx.y;
    int b = bc / CIN, c = bc % CIN;
    __shared__ float xs[16];
    if (threadIdx.x < 16) {
        int i = p * 8 + threadIdx.x;
        if (i > SEQ - 1) i = SEQ - 1;   // edge pad
        xs[threadIdx.x] = (x[(size_t)b * SEQ * CIN + (size_t)i * CIN + c] - mean[bc]) / stdv[bc];
    }
    __syncthreads();
    for (int d = threadIdx.x; d < DM; d += blockDim.x) {
        float acc = 0.f;
        const float* wr = pw + d * 16;
        #pragma unroll
        for (int t = 0; t < 16; t++) acc += xs[t] * wr[t];
        int k2 = d & ~1;
        float ang = (float)p * __expf((float)k2 * PE_COEF);
        acc += (d & 1) ? __cosf(ang) : __sinf(ang);
        size_t idx = ((size_t)bc * NP + p) * DM + d;
        tok[idx] = acc;
        tokb[idx] = f2bf(acc);
    }
}

// ---------------- MFMA GEMM 128x128, 2-phase double-buffered pipeline ----------------
template<int ACT, int OBF>   // ACT: 0 none, 1 fast GELU; OBF: 0 fp32 out, 1 bf16 out
__global__ __launch_bounds__(256) void gemm_mfma(const short* __restrict__ A,
                                                 const short* __restrict__ W,
                                                 const float* __restrict__ bias,
                                                 float* __restrict__ Cf,
                                                 short* __restrict__ Cb,
                                                 int M, int N, int K) {
    __shared__ short LDSU[2][16384];   // [buf][ A:0..8191 | B:8192..16383 ]  64 KB
    int tid = threadIdx.x;
    int w = tid >> 6, lane = tid & 63;
    int row0 = blockIdx.x * 128, col0 = blockIdx.y * 128;
    int wrow = (w >> 1) * 64, wcol = (w & 1) * 64;
    int nt = K >> 6;
    f32x4 acc[4][4] = {};

    auto stage = [&](int b, int kt) {
        #pragma unroll
        for (int i = 0; i < 4; i++) {
            int L = i * 4096 + w * 1024 + lane * 16;    // linear LDS byte offset
            int row = L >> 7;
            int cb  = L & 127;
            int scb = cb ^ ((row & 7) << 4);             // inverse-swizzled source col
            gl_lds16(A + (size_t)(row0 + row) * K + kt + (scb >> 1),
                     (char*)&LDSU[b][0] + i * 4096 + w * 1024);
            gl_lds16(W + (size_t)(col0 + row) * K + kt + (scb >> 1),
                     (char*)&LDSU[b][8192] + i * 4096 + w * 1024);
        }
    };

    stage(0, 0);
    __syncthreads();
    int cur = 0;
    for (int t = 0; t < nt; t++) {
        if (t + 1 < nt) stage(cur ^ 1, (t + 1) * 64);   // prefetch under compute
        const char* Ab = (const char*)&LDSU[cur][0];
        const char* Bb = (const char*)&LDSU[cur][8192];
        #pragma unroll
        for (int ks = 0; ks < 2; ks++) {
            int cb = ks * 64 + ((lane >> 4) << 4);
            short8 af[4], bfr[4];
            #pragma unroll
            for (int m = 0; m < 4; m++) {
                int r = wrow + m * 16 + (lane & 15);
                af[m] = *(const short8*)(Ab + r * 128 + (cb ^ ((r & 7) << 4)));
            }
            #pragma unroll
            for (int n = 0; n < 4; n++) {
                int r = wcol + n * 16 + (lane & 15);
                bfr[n] = *(const short8*)(Bb + r * 128 + (cb ^ ((r & 7) << 4)));
            }
            #pragma unroll
            for (int m = 0; m < 4; m++)
                #pragma unroll
                for (int n = 0; n < 4; n++)
                    acc[m][n] = __builtin_amdgcn_mfma_f32_16x16x32_bf16(af[m], bfr[n], acc[m][n], 0, 0, 0);
        }
        __syncthreads();
        cur ^= 1;
    }

    #pragma unroll
    for (int m = 0; m < 4; m++) {
        int rbase = row0 + wrow + m * 16 + ((lane >> 4) << 2);
        #pragma unroll
        for (int n = 0; n < 4; n++) {
            int col = col0 + wcol + n * 16 + (lane & 15);
            float bval = bias[col];
            #pragma unroll
            for (int j = 0; j < 4; j++) {
                float v = acc[m][n][j] + bval;
                if (ACT == 1) {
                    float u = 0.7978845608f * (v + 0.044715f * v * v * v);
                    float e = exp2f(2.8853900817779268f * u);
                    v = v - v / (e + 1.0f);
                }
                if (OBF) Cb[(size_t)(rbase + j) * N + col] = f2bf(v);
                else     Cf[(size_t)(rbase + j) * N + col] = v;
            }
        }
    }
}

// ---------------- MFMA GEMM 64x128 tile + residual add (for N=512 GEMMs) ----------------
__global__ __launch_bounds__(256) void gemm_mfma64(const short* __restrict__ A,
                                                   const short* __restrict__ W,
                                                   const float* __restrict__ bias,
                                                   const float* __restrict__ resid,
                                                   float* __restrict__ Cf,
                                                   int M, int N, int K) {
    __shared__ short LDSU[2][12288];   // [buf][ A:0..4095 sh | B:4096..12287 sh ] 48 KB
    int tid = threadIdx.x;
    int w = tid >> 6, lane = tid & 63;
    int row0 = blockIdx.x * 64, col0 = blockIdx.y * 128;
    int nt = K >> 6;
    f32x4 acc[4][2] = {};

    auto stage = [&](int b, int kt) {
        #pragma unroll
        for (int i = 0; i < 2; i++) {
            int L = (i * 4 + w) * 1024 + lane * 16;
            int row = L >> 7, cb = L & 127;
            int scb = cb ^ ((row & 7) << 4);
            gl_lds16(A + (size_t)(row0 + row) * K + kt + (scb >> 1),
                     (char*)&LDSU[b][0] + (i * 4 + w) * 1024);
        }
        #pragma unroll
        for (int i = 0; i < 4; i++) {
            int L = (i * 4 + w) * 1024 + lane * 16;
            int row = L >> 7, cb = L & 127;
            int scb = cb ^ ((row & 7) << 4);
            gl_lds16(W + (size_t)(col0 + row) * K + kt + (scb >> 1),
                     (char*)&LDSU[b][4096] + (i * 4 + w) * 1024);
        }
    };

    stage(0, 0);
    __syncthreads();
    int cur = 0;
    for (int t = 0; t < nt; t++) {
        if (t + 1 < nt) stage(cur ^ 1, (t + 1) * 64);
        const char* Ab = (const char*)&LDSU[cur][0];
        const char* Bb = (const char*)&LDSU[cur][4096];
        #pragma unroll
        for (int ks = 0; ks < 2; ks++) {
            int cb = ks * 64 + ((lane >> 4) << 4);
            short8 af[4], bfr[2];
            #pragma unroll
            for (int m = 0; m < 4; m++) {
                int r = m * 16 + (lane & 15);
                af[m] = *(const short8*)(Ab + r * 128 + (cb ^ ((r & 7) << 4)));
            }
            #pragma unroll
            for (int n = 0; n < 2; n++) {
                int r = w * 32 + n * 16 + (lane & 15);
                bfr[n] = *(const short8*)(Bb + r * 128 + (cb ^ ((r & 7) << 4)));
            }
            #pragma unroll
            for (int m = 0; m < 4; m++)
                #pragma unroll
                for (int n = 0; n < 2; n++)
                    acc[m][n] = __builtin_amdgcn_mfma_f32_16x16x32_bf16(af[m], bfr[n], acc[m][n], 0, 0, 0);
        }
        __syncthreads();
        cur ^= 1;
    }

    #pragma unroll
    for (int m = 0; m < 4; m++) {
        int rbase = row0 + m * 16 + ((lane >> 4) << 2);
        #pragma unroll
        for (int n = 0; n < 2; n++) {
            int col = col0 + w * 32 + n * 16 + (lane & 15);
            float bval = bias[col];
            #pragma unroll
            for (int j = 0; j < 4; j++) {
                float v = acc[m][n][j] + bval;
                v += resid[(size_t)(rbase + j) * N + col];
                Cf[(size_t)(rbase + j) * N + col] = v;
            }
        }
    }
}

// ---------------- fused ProbSparse attention (one block per (bc,h)) ----------------
__global__ __launch_bounds__(256, 2) void attn_fused(const short* __restrict__ qkvb,
                                                     const int* __restrict__ samp,
                                                     short* __restrict__ ctxb) {
    __shared__ float Sbuf[64 * 130];   // 33.28 KB; overlays Stop[32*130] + Pb
    __shared__ short Vt[64 * 128];     // 16 KB, XOR-swizzled rows of 256 B
    __shared__ short Kls[128 * 64];    // 16 KB, XOR-swizzled rows of 128 B
    __shared__ float Mv[128];
    __shared__ int   topl[32];
    __shared__ float vmean[64];
    __shared__ float vpart[256];

    float* Stop = Sbuf;                          // 32 x 130 fp32
    short* Pb   = (short*)(Sbuf + 32 * 130);     // 32 x 128 bf16, XOR-swizzled

    int bh = blockIdx.x, bc = bh >> 3, h = bh & 7;
    int tid = threadIdx.x, w = tid >> 6, lane = tid & 63;
    const short* base = qkvb + (size_t)bc * NP * 1536 + h * DH;
    short* cbase = ctxb + (size_t)bc * NP * DM + h * DH;

    // P0: stage K (swizzled rows) + V transposed (swizzled)
    for (int e = tid; e < 1024; e += 256) {
        int row = e >> 3, c8 = e & 7;
        short8 kv = *(const short8*)(base + (size_t)row * 1536 + 512 + c8 * 8);
        *(short8*)((char*)Kls + row * 128 + ((c8 * 16) ^ ((row & 7) << 4))) = kv;
        short8 vv = *(const short8*)(base + (size_t)row * 1536 + 1024 + c8 * 8);
        #pragma unroll
        for (int j = 0; j < 8; j++) {
            int d = c8 * 8 + j;
            *(short*)((char*)Vt + d * 256 + ((2 * row) ^ ((d & 7) << 4))) = vv[j];
        }
    }
    __syncthreads();
    {
        int d = tid & 63, part = tid >> 6;
        float s = 0.f;
        #pragma unroll
        for (int i4 = 0; i4 < 4; i4++) {
            short8 v = *(const short8*)((char*)Vt + d * 256 + ((part * 64 + i4 * 16) ^ ((d & 7) << 4)));
            #pragma unroll
            for (int j = 0; j < 8; j++) s += bf2f(v[j]);
        }
        vpart[part * 64 + d] = s;
    }

    // P2: S halves (64 rows each) + M-score gather per half
    for (int half = 0; half < 2; half++) {
        int ar = half * 64 + 16 * w + (lane & 15);
        const short* qp = base + (size_t)ar * 1536;
        short8 a0 = *(const short8*)(qp + (lane >> 4) * 8);
        short8 a1 = *(const short8*)(qp + 32 + (lane >> 4) * 8);
        #pragma unroll 2
        for (int ct = 0; ct < 8; ct++) {
            int br = ct * 16 + (lane & 15);
            int cb0 = (lane >> 4) * 16;
            short8 b0 = *(const short8*)((char*)Kls + br * 128 + (cb0 ^ ((br & 7) << 4)));
            short8 b1 = *(const short8*)((char*)Kls + br * 128 + ((cb0 + 64) ^ ((br & 7) << 4)));
            f32x4 acc = {};
            acc = __builtin_amdgcn_mfma_f32_16x16x32_bf16(a0, b0, acc, 0, 0, 0);
            acc = __builtin_amdgcn_mfma_f32_16x16x32_bf16(a1, b1, acc, 0, 0, 0);
            int r0 = 16 * w + ((lane >> 4) << 2);
            int c = ct * 16 + (lane & 15);
            #pragma unroll
            for (int j = 0; j < 4; j++) Sbuf[(r0 + j) * 130 + c] = acc[j] * 0.125f;
        }
        __syncthreads();
        if (tid < 64) {
            int r = half * 64 + tid;
            const int* sp = samp + r * U;
            const float* Srow = &Sbuf[tid * 130];
            float mx = -1e30f, sm = 0.f;
            #pragma unroll
            for (int s = 0; s < U; s++) { float v = Srow[sp[s]]; mx = fmaxf(mx, v); sm += v; }
            Mv[r] = mx - sm * (1.0f / U);
        } else if (half == 0 && tid < 128) {
            int d = tid - 64;
            vmean[d] = (vpart[d] + vpart[64 + d] + vpart[128 + d] + vpart[192 + d]) * (1.0f / 128.0f);
        }
        __syncthreads();
    }

    // P6: wave0 = top-25 shuffle argmax; waves 1-3 = broadcast vmean to ALL ctx rows
    if (w == 0) {
        float v0 = Mv[lane], v1 = Mv[lane + 64];
        for (int it = 0; it < U; it++) {
            float bv; int bi;
            if (v1 > v0) { bv = v1; bi = lane + 64; } else { bv = v0; bi = lane; }
            #pragma unroll
            for (int o = 32; o > 0; o >>= 1) {
                float ov = __shfl_xor(bv, o);
                int   oi = __shfl_xor(bi, o);
                if (ov > bv || (ov == bv && oi < bi)) { bv = ov; bi = oi; }
            }
            if (lane == 0) topl[it] = bi;
            if (bi == lane) v0 = -1e30f;
            if (bi == lane + 64) v1 = -1e30f;
        }
    } else {
        for (int e = tid - 64; e < 128 * 16; e += 192) {
            int n = e >> 4, c4 = e & 15;
            short4 o;
            o.x = f2bf(vmean[c4 * 4 + 0]); o.y = f2bf(vmean[c4 * 4 + 1]);
            o.z = f2bf(vmean[c4 * 4 + 2]); o.w = f2bf(vmean[c4 * 4 + 3]);
            *(short4*)(cbase + (size_t)n * DM + c4 * 4) = o;
        }
    }
    __syncthreads();

    // P7: recompute scores for the 25 top rows into Stop
    {
        int rt = w & 1, cth = w >> 1;
        int u = rt * 16 + (lane & 15);
        int qrow = topl[u < U ? u : U - 1];
        const short* qp = base + (size_t)qrow * 1536;
        short8 a0 = *(const short8*)(qp + (lane >> 4) * 8);
        short8 a1 = *(const short8*)(qp + 32 + (lane >> 4) * 8);
        #pragma unroll
        for (int cti = 0; cti < 4; cti++) {
            int ct = cth * 4 + cti;
            int br = ct * 16 + (lane & 15);
            int cb0 = (lane >> 4) * 16;
            short8 b0 = *(const short8*)((char*)Kls + br * 128 + (cb0 ^ ((br & 7) << 4)));
            short8 b1 = *(const short8*)((char*)Kls + br * 128 + ((cb0 + 64) ^ ((br & 7) << 4)));
            f32x4 acc = {};
            acc = __builtin_amdgcn_mfma_f32_16x16x32_bf16(a0, b0, acc, 0, 0, 0);
            acc = __builtin_amdgcn_mfma_f32_16x16x32_bf16(a1, b1, acc, 0, 0, 0);
            int r0 = rt * 16 + ((lane >> 4) << 2);
            int c = ct * 16 + (lane & 15);
            #pragma unroll
            for (int j = 0; j < 4; j++) Stop[(r0 + j) * 130 + c] = acc[j] * 0.125f;
        }
    }
    __syncthreads();

    // P8: softmax of top rows -> Pb (bf16, swizzled); zero pad rows 25..31
    for (int e = tid; e < 7 * 128; e += 256)
        Pb[(25 + (e >> 7)) * 128 + (e & 127)] = 0;
    for (int it = w; it < U; it += 4) {
        float s0 = Stop[it * 130 + lane], s1 = Stop[it * 130 + 64 + lane];
        float mx = fmaxf(s0, s1);
        #pragma unroll
        for (int o = 32; o > 0; o >>= 1) mx = fmaxf(mx, __shfl_xor(mx, o));
        float e0 = expf(s0 - mx), e1 = expf(s1 - mx);
        float sum = e0 + e1;
        #pragma unroll
        for (int o = 32; o > 0; o >>= 1) sum += __shfl_xor(sum, o);
        float inv = 1.0f / sum;
        int sw = (it & 7) << 4;
        *(short*)((char*)Pb + it * 256 + ((2 * lane) ^ sw))        = f2bf(e0 * inv);
        *(short*)((char*)Pb + it * 256 + ((2 * (64 + lane)) ^ sw)) = f2bf(e1 * inv);
    }
    __syncthreads();

    // P9: PV via MFMA, scatter to top rows
    #pragma unroll
    for (int t = w * 2; t < w * 2 + 2; t++) {
        int rt = t >> 2, ct = t & 3;
        int pr = rt * 16 + (lane & 15);
        int vr = ct * 16 + (lane & 15);
        f32x4 acc = {};
        #pragma unroll
        for (int ks = 0; ks < 4; ks++) {
            int off = ks * 64 + (lane >> 4) * 16;
            short8 a = *(const short8*)((char*)Pb + pr * 256 + (off ^ ((pr & 7) << 4)));
            short8 b = *(const short8*)((char*)Vt + vr * 256 + (off ^ ((vr & 7) << 4)));
            acc = __builtin_amdgcn_mfma_f32_16x16x32_bf16(a, b, acc, 0, 0, 0);
        }
        int u0 = rt * 16 + ((lane >> 4) << 2), d = ct * 16 + (lane & 15);
        #pragma unroll
        for (int j = 0; j < 4; j++) {
            int u = u0 + j;
            if (u < U) cbase[(size_t)topl[u] * DM + d] = f2bf(acc[j]);
        }
    }
}

// ---------------- LayerNorm (input already has residual folded; outs nullable) ----------------
__global__ __launch_bounds__(256) void residual_ln(const float* __restrict__ a,
                                                   const float* __restrict__ g,
                                                   const float* __restrict__ beta,
                                                   float* __restrict__ out,
                                                   short* __restrict__ outb) {
    int row = blockIdx.x;
    int tid = threadIdx.x;
    const float* ar = a + (size_t)row * DM;
    float x0 = ar[tid], x1 = ar[tid + 256];
    __shared__ float rs[256], rss[256];
    rs[tid] = x0 + x1; rss[tid] = x0 * x0 + x1 * x1; __syncthreads();
    for (int o = 128; o > 0; o >>= 1) {
        if (tid < o) { rs[tid] += rs[tid + o]; rss[tid] += rss[tid + o]; }
        __syncthreads();
    }
    float m = rs[0] / DM;
    float var = rss[0] / DM - m * m;
    float r = rsqrtf(var + 1e-5f);
    float y0 = (x0 - m) * r * g[tid] + beta[tid];
    float y1 = (x1 - m) * r * g[tid + 256] + beta[tid + 256];
    if (out) {
        out[(size_t)row * DM + tid]       = y0;
        out[(size_t)row * DM + tid + 256] = y1;
    }
    if (outb) {
        outb[(size_t)row * DM + tid]       = f2bf(y0);
        outb[(size_t)row * DM + tid + 256] = f2bf(y1);
    }
}

// ---------------- transpose tokb(bc,p,d) bf16 -> featb(bc,d,p) bf16 ----------------
__global__ void transpose_tok(const short* __restrict__ tokb, short* __restrict__ featb) {
    __shared__ short t[32][34];
    int bc = blockIdx.z, dt = blockIdx.y, pt = blockIdx.x;
    int tx = threadIdx.x, ty = threadIdx.y;
    #pragma unroll
    for (int i = 0; i < 4; i++) {
        int p = pt * 32 + ty + i * 8;
        int d = dt * 32 + tx;
        t[ty + i * 8][tx] = tokb[((size_t)bc * NP + p) * DM + d];
    }
    __syncthreads();
    #pragma unroll
    for (int i = 0; i < 4; i++) {
        int d = dt * 32 + ty + i * 8;
        int p = pt * 32 + tx;
        featb[(size_t)bc * (DM * NP) + (size_t)d * NP + p] = t[tx][ty + i * 8];
    }
}

// ---------------- head MFMA split-K: partial[blk][96][64] ----------------
__global__ __launch_bounds__(256) void head_mfma(const float* __restrict__ hw,
                                                 const short* __restrict__ featb,
                                                 float* __restrict__ partial) {
    __shared__ short Als[96 * 64];
    __shared__ short Bls[64 * 64];
    int tid = threadIdx.x;
    int w = tid >> 6, lane = tid & 63;
    int wm = w >> 1, wn = w & 1;
    int kb = blockIdx.x * HKB;
    f32x4 acc[3][2] = {};
    const char* Ab = (const char*)Als;
    const char* Bb = (const char*)Bls;

    for (int kt = 0; kt < HKB; kt += 64) {
        #pragma unroll
        for (int i = 0; i < 6; i++) {
            int s = tid + i * 256;
            int row = s >> 4, c4 = s & 15;
            float4 v = *(const float4*)(hw + (size_t)row * 65536 + kb + kt + c4 * 4);
            short4 o; o.x = f2bf(v.x); o.y = f2bf(v.y); o.z = f2bf(v.z); o.w = f2bf(v.w);
            int boff = row * 128 + ((c4 * 8) ^ ((row & 7) << 4));
            *(short4*)((char*)Als + boff) = o;
        }
        #pragma unroll
        for (int i = 0; i < 4; i++) {
            int s = tid + i * 256;
            int row = s >> 4, c4 = s & 15;
            short4 o;
            if (row < BC) o = *(const short4*)(featb + (size_t)row * 65536 + kb + kt + c4 * 4);
            else { o.x = 0; o.y = 0; o.z = 0; o.w = 0; }
            int boff = row * 128 + ((c4 * 8) ^ ((row & 7) << 4));
            *(short4*)((char*)Bls + boff) = o;
        }
        __syncthreads();
        #pragma unroll
        for (int ks = 0; ks < 2; ks++) {
            int cb = ks * 64 + ((lane >> 4) << 4);
            short8 af[3], bfr[2];
            #pragma unroll
            for (int m = 0; m < 3; m++) {
                int r = wm * 48 + m * 16 + (lane & 15);
                af[m] = *(const short8*)(Ab + r * 128 + (cb ^ ((r & 7) << 4)));
            }
            #pragma unroll
            for (int n = 0; n < 2; n++) {
                int r = wn * 32 + n * 16 + (lane & 15);
                bfr[n] = *(const short8*)(Bb + r * 128 + (cb ^ ((r & 7) << 4)));
            }
            #pragma unroll
            for (int m = 0; m < 3; m++)
                #pragma unroll
                for (int n = 0; n < 2; n++)
                    acc[m][n] = __builtin_amdgcn_mfma_f32_16x16x32_bf16(af[m], bfr[n], acc[m][n], 0, 0, 0);
        }
        __syncthreads();
    }

    float* pb = partial + (size_t)blockIdx.x * (96 * 64);
    #pragma unroll
    for (int m = 0; m < 3; m++) {
        int rbase = wm * 48 + m * 16 + ((lane >> 4) << 2);
        #pragma unroll
        for (int n = 0; n < 2; n++) {
            int col = wn * 32 + n * 16 + (lane & 15);
            #pragma unroll
            for (int j = 0; j < 4; j++)
                pb[(rbase + j) * 64 + col] = acc[m][n][j];
        }
    }
}

// ---------------- finalize: 2-stage split-K reduction + bias + de-norm ----------------
__global__ void finalize_a(const float* __restrict__ partial, float* __restrict__ p2) {
    int i = blockIdx.x * 256 + threadIdx.x;   // 0..6143
    int s = blockIdx.y;                        // 0..7
    const float* p = partial + (size_t)s * 32 * 6144 + i;
    float sum = 0.f;
    #pragma unroll
    for (int b = 0; b < 32; b++) sum += p[(size_t)b * 6144];
    p2[s * 6144 + i] = sum;
}

__global__ void finalize_b(const float* __restrict__ p2, const float* __restrict__ hb,
                           const float* __restrict__ mean, const float* __restrict__ stdv,
                           float* __restrict__ out) {
    int i = blockIdx.x * 256 + threadIdx.x;
    if (i >= NB * 96 * CIN) return;
    int b = i / (96 * CIN);
    int r = i % (96 * CIN);
    int t = r / CIN, c = r % CIN;
    int bc = b * CIN + c;
    int j = t * 64 + bc;
    float s = 0.f;
    #pragma unroll
    for (int k = 0; k < 8; k++) s += p2[k * 6144 + j];
    out[i] = (s + hb[t]) * stdv[bc] + mean[bc];
}

// ---------------- launch ----------------
extern "C" void kernel_launch(void* const* d_in, const int* in_sizes, int n_in,
                              void* d_out, int out_size, void* d_ws, size_t ws_size,
                              hipStream_t stream) {
    (void)in_sizes; (void)n_in; (void)out_size; (void)ws_size;
    const float* x_enc   = (const float*)d_in[0];
    const float* patch_W = (const float*)d_in[4];
    const float* Wq  = (const float*)d_in[5];
    const float* bq  = (const float*)d_in[6];
    const float* Wk  = (const float*)d_in[7];
    const float* bk  = (const float*)d_in[8];
    const float* Wv  = (const float*)d_in[9];
    const float* bv  = (const float*)d_in[10];
    const float* Wo  = (const float*)d_in[11];
    const float* bo  = (const float*)d_in[12];
    const float* c1W = (const float*)d_in[13];
    const float* c1b = (const float*)d_in[14];
    const float* c2W = (const float*)d_in[15];
    const float* c2b = (const float*)d_in[16];
    const float* ln1g = (const float*)d_in[17];
    const float* ln1b = (const float*)d_in[18];
    const float* ln2g = (const float*)d_in[19];
    const float* ln2b = (const float*)d_in[20];
    const float* encg = (const float*)d_in[21];
    const float* encb = (const float*)d_in[22];
    const float* headW = (const float*)d_in[23];
    const float* headb = (const float*)d_in[24];
    float* out = (float*)d_out;

    float* ws = (float*)d_ws;
    float* mean = ws + 0;
    float* stdv = ws + 64;
    float* bqkv = ws + 128;                 // 2*1536 floats
    int*   samp = (int*)(ws + 6144);        // 6400 ints
    size_t off = 32768;
    const size_t T = (size_t)NTOK * DM;     // 3,670,016
    float* tok     = ws + off; off += T;
    float* pA      = ws + off; off += T;      // GEMM fp32 out (Wo / FFN2, residual folded)
    float* x1      = ws + off; off += T;      // also reused as p2 in head phase
    float* partial = ws + off; off += T;      // head split-K partials (256*6144)
    float* p2      = x1;
    // bf16 region
    short* sbase = (short*)(ws + off);
    size_t soff = 0;
    short* tok_b  = sbase + soff; soff += T;
    short* ctx_b  = sbase + soff; soff += T;
    short* x1_b   = sbase + soff; soff += T;
    short* qkv_b  = sbase + soff; soff += 3 * T;            // bf16 QKV
    short* ffn_b  = sbase + soff; soff += (size_t)NTOK * DFF;
    short* featb  = ffn_b;                  // reuse: ffn_b dead after encoder loop
    short* wqkv_b = sbase + soff; soff += 2 * 1536 * DM;
    short* wo_b   = sbase + soff; soff += 2 * DM * DM;
    short* c1w_b  = sbase + soff; soff += 2 * (size_t)DFF * DM;
    short* c2w_b  = sbase + soff; soff += 2 * (size_t)DM * DFF;

    stats_kernel<<<BC, 256, 0, stream>>>(x_enc, mean, stdv);
    prep_weights<<<6146, 256, 0, stream>>>(Wq, Wk, Wv, bq, bk, bv, Wo, c1W, c2W,
                                           wqkv_b, bqkv, wo_b, c1w_b, c2w_b, samp);
    patch_embed<<<dim3(NP, BC), 128, 0, stream>>>(x_enc, patch_W, mean, stdv, tok, tok_b);

    for (int l = 0; l < 2; l++) {
        // QKV (bf16 out)
        gemm_mfma<0,1><<<dim3(56, 12), 256, 0, stream>>>(tok_b, wqkv_b + (size_t)l * 1536 * DM, bqkv + l * 1536, nullptr, qkv_b, NTOK, 1536, DM);
        attn_fused<<<448, 256, 0, stream>>>(qkv_b, samp + l * 3200, ctx_b);
        // Wo + residual(tok) folded -> pA; then LN1 -> x1 + x1_b
        gemm_mfma64<<<dim3(112, 4), 256, 0, stream>>>(ctx_b, wo_b + (size_t)l * DM * DM, bo + l * DM, tok, pA, NTOK, DM, DM);
        residual_ln<<<NTOK, 256, 0, stream>>>(pA, ln1g + l * DM, ln1b + l * DM, x1, x1_b);
        gemm_mfma<1,1><<<dim3(56, 16), 256, 0, stream>>>(x1_b, c1w_b + (size_t)l * DFF * DM, c1b + l * DFF, nullptr, ffn_b, NTOK, DFF, DM);
        // FFN2 + residual(x1) folded -> pA; then LN2 -> tok + tok_b
        gemm_mfma64<<<dim3(112, 4), 256, 0, stream>>>(ffn_b, c2w_b + (size_t)l * DM * DFF, c2b + l * DM, x1, pA, NTOK, DM, DFF);
        residual_ln<<<NTOK, 256, 0, stream>>>(pA, ln2g + l * DM, ln2b + l * DM, tok, tok_b);
    }

    // final encoder LN: bf16 out only
    residual_ln<<<NTOK, 256, 0, stream>>>(tok, encg, encb, nullptr, tok_b);
    transpose_tok<<<dim3(4, 16, BC), dim3(32, 8), 0, stream>>>(tok_b, featb);
    head_mfma<<<HNB, 256, 0, stream>>>(headW, featb, partial);
    finalize_a<<<dim3(24, 8), 256, 0, stream>>>(partial, p2);
    finalize_b<<<21, 256, 0, stream>>>(p2, headb, mean, stdv, out);
}

// Round 11
// 309.330 us; speedup vs baseline: 1.3686x; 1.0387x over previous
//
#include <hip/hip_runtime.h>
#include <math.h>
#include <stdint.h>

#define SEQ   1024
#define CIN   7
#define NB    8
#define BC    56          // NB*CIN
#define NP    128         // patches
#define DM    512
#define NH    8
#define DH    64
#define DFF   2048
#define U     25
#define NTOK  (BC*NP)     // 7168
#define PE_COEF (-9.210340371976184f / 512.0f)  // -ln(10000)/DM
#define HKB   256         // head: K elems per split-K block
#define HNB   256         // head: number of split-K blocks (HKB*HNB = 65536)

typedef __attribute__((ext_vector_type(8))) short short8;
typedef __attribute__((ext_vector_type(4))) float f32x4;

__device__ __forceinline__ short f2bf(float x) {
    union { float f; uint32_t u; } v; v.f = x;
    uint32_t r = v.u + 0x7FFFu + ((v.u >> 16) & 1u);
    return (short)(r >> 16);
}
__device__ __forceinline__ float bf2f(short x) {
    union { uint32_t u; float f; } v; v.u = ((uint32_t)(uint16_t)x) << 16;
    return v.f;
}

__device__ __forceinline__ void gl_lds16(const void* g, void* s) {
    __builtin_amdgcn_global_load_lds((const __attribute__((address_space(1))) void*)g,
                                     (__attribute__((address_space(3))) void*)s, 16, 0, 0);
}

// ---------------- stats: per (b,c) mean/std over SEQ ----------------
__global__ void stats_kernel(const float* __restrict__ x, float* __restrict__ mean,
                             float* __restrict__ stdv) {
    int bc = blockIdx.x; int b = bc / CIN, c = bc % CIN;
    const float* base = x + (size_t)b * SEQ * CIN + c;
    float s = 0.f, ss = 0.f;
    for (int i = threadIdx.x; i < SEQ; i += 256) {
        float v = base[(size_t)i * CIN];
        s += v; ss += v * v;
    }
    __shared__ float rs[256], rss[256];
    rs[threadIdx.x] = s; rss[threadIdx.x] = ss; __syncthreads();
    for (int o = 128; o > 0; o >>= 1) {
        if (threadIdx.x < o) { rs[threadIdx.x] += rs[threadIdx.x + o]; rss[threadIdx.x] += rss[threadIdx.x + o]; }
        __syncthreads();
    }
    if (threadIdx.x == 0) {
        float m = rs[0] / SEQ;
        float v = rss[0] / SEQ - m * m;
        mean[bc] = m;
        stdv[bc] = sqrtf(v + 1e-5f);
    }
}

// ---------------- threefry2x32-20 (JAX PRNG) ----------------
__device__ __forceinline__ void tf_round(uint32_t& x0, uint32_t& x1, uint32_t r) {
    x0 += x1; x1 = (x1 << r) | (x1 >> (32u - r)); x1 ^= x0;
}
__device__ void threefry2x32(uint32_t k0, uint32_t k1, uint32_t x0, uint32_t x1,
                             uint32_t& o0, uint32_t& o1) {
    uint32_t ks[3] = { k0, k1, k0 ^ k1 ^ 0x1BD11BDAu };
    x0 += ks[0]; x1 += ks[1];
    const uint32_t rotA[4] = {13u, 15u, 26u, 6u}, rotB[4] = {17u, 29u, 16u, 24u};
    #pragma unroll
    for (int i = 0; i < 5; i++) {
        const uint32_t* rr = (i & 1) ? rotB : rotA;
        tf_round(x0, x1, rr[0]); tf_round(x0, x1, rr[1]);
        tf_round(x0, x1, rr[2]); tf_round(x0, x1, rr[3]);
        x0 += ks[(i + 1) % 3];
        x1 += ks[(i + 2) % 3] + (uint32_t)(i + 1);
    }
    o0 = x0; o1 = x1;
}

// ---------------- fused prep: pack QKV weights, convert Wo/c1W/c2W, samp ----------------
__global__ void prep_weights(const float* __restrict__ Wq, const float* __restrict__ Wk,
                             const float* __restrict__ Wv, const float* __restrict__ bq,
                             const float* __restrict__ bk, const float* __restrict__ bv,
                             const float* __restrict__ Wo, const float* __restrict__ c1W,
                             const float* __restrict__ c2W,
                             short* __restrict__ wqkv, float* __restrict__ bqkv,
                             short* __restrict__ wo_b, short* __restrict__ c1w_b,
                             short* __restrict__ c2w_b, int* __restrict__ samp) {
    int blk = blockIdx.x, tid = threadIdx.x;
    if (blk < 1536) {                       // pack_qkv: 2*1536*128 float4 slots
        int idx = blk * 256 + tid;
        int k4 = idx & 127;
        int n  = (idx >> 7) % 1536;
        int l  = idx / (1536 * 128);
        int sel3 = n >> 9;
        int nn = n & 511;
        const float* src = sel3 == 0 ? Wq : sel3 == 1 ? Wk : Wv;
        float4 v = *(const float4*)(src + ((size_t)l * DM + nn) * DM + k4 * 4);
        short4 o; o.x = f2bf(v.x); o.y = f2bf(v.y); o.z = f2bf(v.z); o.w = f2bf(v.w);
        *(short4*)(wqkv + ((size_t)l * 1536 + n) * DM + k4 * 4) = o;
        if (k4 == 0) {
            const float* bsrc = sel3 == 0 ? bq : sel3 == 1 ? bk : bv;
            bqkv[l * 1536 + n] = bsrc[l * DM + nn];
        }
    } else if (blk < 6144) {                // converts
        const float* in; short* out; int i;
        if (blk < 2048)      { in = Wo;  out = wo_b;  i = (blk - 1536) * 256 + tid; }
        else if (blk < 4096) { in = c1W; out = c1w_b; i = (blk - 2048) * 256 + tid; }
        else                 { in = c2W; out = c2w_b; i = (blk - 4096) * 256 + tid; }
        float4 v = ((const float4*)in)[i];
        short4 o; o.x = f2bf(v.x); o.y = f2bf(v.y); o.z = f2bf(v.z); o.w = f2bf(v.w);
        ((short4*)out)[i] = o;
    } else {                                 // samp: 2 blocks
        int l = blk - 6144;
        uint32_t s0, s1; threefry2x32(0u, 42u, 0u, (uint32_t)l, s0, s1);
        uint32_t a0, a1, b0, b1;
        threefry2x32(s0, s1, 0u, 2u, a0, a1);
        threefry2x32(s0, s1, 1u, 3u, b0, b1);
        uint32_t k20 = a1, k21 = b1;
        for (int i = tid; i < 1600; i += 256) {
            uint32_t o0, o1;
            threefry2x32(k20, k21, (uint32_t)i, (uint32_t)(1600 + i), o0, o1);
            samp[l * 3200 + i]        = (int)(o0 & 127u);
            samp[l * 3200 + 1600 + i] = (int)(o1 & 127u);
        }
    }
}

// ---------------- patch embedding + sinusoidal PE (bf16 out) ----------------
__global__ void patch_embed(const float* __restrict__ x, const float* __restrict__ pw,
                            const float* __restrict__ mean, const float* __restrict__ stdv,
                            short* __restrict__ tokb) {
    int p = blockIdx.x, bc = blockIdx.y;
    int b = bc / CIN, c = bc % CIN;
    __shared__ float xs[16];
    if (threadIdx.x < 16) {
        int i = p * 8 + threadIdx.x;
        if (i > SEQ - 1) i = SEQ - 1;   // edge pad
        xs[threadIdx.x] = (x[(size_t)b * SEQ * CIN + (size_t)i * CIN + c] - mean[bc]) / stdv[bc];
    }
    __syncthreads();
    for (int d = threadIdx.x; d < DM; d += blockDim.x) {
        float acc = 0.f;
        const float* wr = pw + d * 16;
        #pragma unroll
        for (int t = 0; t < 16; t++) acc += xs[t] * wr[t];
        int k2 = d & ~1;
        float ang = (float)p * __expf((float)k2 * PE_COEF);
        acc += (d & 1) ? __cosf(ang) : __sinf(ang);
        tokb[((size_t)bc * NP + p) * DM + d] = f2bf(acc);
    }
}

// ---------------- MFMA GEMM 128x128, 2-phase double-buffered pipeline ----------------
template<int ACT>   // ACT: 0 none, 1 fast GELU; bf16 out
__global__ __launch_bounds__(256) void gemm_mfma(const short* __restrict__ A,
                                                 const short* __restrict__ W,
                                                 const float* __restrict__ bias,
                                                 short* __restrict__ Cb,
                                                 int M, int N, int K) {
    __shared__ short LDSU[2][16384];   // [buf][ A:0..8191 | B:8192..16383 ]  64 KB
    int tid = threadIdx.x;
    int w = tid >> 6, lane = tid & 63;
    int row0 = blockIdx.x * 128, col0 = blockIdx.y * 128;
    int wrow = (w >> 1) * 64, wcol = (w & 1) * 64;
    int nt = K >> 6;
    f32x4 acc[4][4] = {};

    auto stage = [&](int b, int kt) {
        #pragma unroll
        for (int i = 0; i < 4; i++) {
            int L = i * 4096 + w * 1024 + lane * 16;    // linear LDS byte offset
            int row = L >> 7;
            int cb  = L & 127;
            int scb = cb ^ ((row & 7) << 4);             // inverse-swizzled source col
            gl_lds16(A + (size_t)(row0 + row) * K + kt + (scb >> 1),
                     (char*)&LDSU[b][0] + i * 4096 + w * 1024);
            gl_lds16(W + (size_t)(col0 + row) * K + kt + (scb >> 1),
                     (char*)&LDSU[b][8192] + i * 4096 + w * 1024);
        }
    };

    stage(0, 0);
    __syncthreads();
    int cur = 0;
    for (int t = 0; t < nt; t++) {
        if (t + 1 < nt) stage(cur ^ 1, (t + 1) * 64);   // prefetch under compute
        const char* Ab = (const char*)&LDSU[cur][0];
        const char* Bb = (const char*)&LDSU[cur][8192];
        #pragma unroll
        for (int ks = 0; ks < 2; ks++) {
            int cb = ks * 64 + ((lane >> 4) << 4);
            short8 af[4], bfr[4];
            #pragma unroll
            for (int m = 0; m < 4; m++) {
                int r = wrow + m * 16 + (lane & 15);
                af[m] = *(const short8*)(Ab + r * 128 + (cb ^ ((r & 7) << 4)));
            }
            #pragma unroll
            for (int n = 0; n < 4; n++) {
                int r = wcol + n * 16 + (lane & 15);
                bfr[n] = *(const short8*)(Bb + r * 128 + (cb ^ ((r & 7) << 4)));
            }
            #pragma unroll
            for (int m = 0; m < 4; m++)
                #pragma unroll
                for (int n = 0; n < 4; n++)
                    acc[m][n] = __builtin_amdgcn_mfma_f32_16x16x32_bf16(af[m], bfr[n], acc[m][n], 0, 0, 0);
        }
        __syncthreads();
        cur ^= 1;
    }

    #pragma unroll
    for (int m = 0; m < 4; m++) {
        int rbase = row0 + wrow + m * 16 + ((lane >> 4) << 2);
        #pragma unroll
        for (int n = 0; n < 4; n++) {
            int col = col0 + wcol + n * 16 + (lane & 15);
            float bval = bias[col];
            #pragma unroll
            for (int j = 0; j < 4; j++) {
                float v = acc[m][n][j] + bval;
                if (ACT == 1) {
                    float u = 0.7978845608f * (v + 0.044715f * v * v * v);
                    float e = exp2f(2.8853900817779268f * u);
                    v = v - v / (e + 1.0f);
                }
                Cb[(size_t)(rbase + j) * N + col] = f2bf(v);
            }
        }
    }
}

// ---------------- MFMA GEMM 64x128 tile + bf16 residual add, bf16 out ----------------
__global__ __launch_bounds__(256) void gemm_mfma64(const short* __restrict__ A,
                                                   const short* __restrict__ W,
                                                   const float* __restrict__ bias,
                                                   const short* __restrict__ residb,
                                                   short* __restrict__ Cb,
                                                   int M, int N, int K) {
    __shared__ short LDSU[2][12288];   // [buf][ A:0..4095 sh | B:4096..12287 sh ] 48 KB
    int tid = threadIdx.x;
    int w = tid >> 6, lane = tid & 63;
    int row0 = blockIdx.x * 64, col0 = blockIdx.y * 128;
    int nt = K >> 6;
    f32x4 acc[4][2] = {};

    auto stage = [&](int b, int kt) {
        #pragma unroll
        for (int i = 0; i < 2; i++) {
            int L = (i * 4 + w) * 1024 + lane * 16;
            int row = L >> 7, cb = L & 127;
            int scb = cb ^ ((row & 7) << 4);
            gl_lds16(A + (size_t)(row0 + row) * K + kt + (scb >> 1),
                     (char*)&LDSU[b][0] + (i * 4 + w) * 1024);
        }
        #pragma unroll
        for (int i = 0; i < 4; i++) {
            int L = (i * 4 + w) * 1024 + lane * 16;
            int row = L >> 7, cb = L & 127;
            int scb = cb ^ ((row & 7) << 4);
            gl_lds16(W + (size_t)(col0 + row) * K + kt + (scb >> 1),
                     (char*)&LDSU[b][4096] + (i * 4 + w) * 1024);
        }
    };

    stage(0, 0);
    __syncthreads();
    int cur = 0;
    for (int t = 0; t < nt; t++) {
        if (t + 1 < nt) stage(cur ^ 1, (t + 1) * 64);
        const char* Ab = (const char*)&LDSU[cur][0];
        const char* Bb = (const char*)&LDSU[cur][4096];
        #pragma unroll
        for (int ks = 0; ks < 2; ks++) {
            int cb = ks * 64 + ((lane >> 4) << 4);
            short8 af[4], bfr[2];
            #pragma unroll
            for (int m = 0; m < 4; m++) {
                int r = m * 16 + (lane & 15);
                af[m] = *(const short8*)(Ab + r * 128 + (cb ^ ((r & 7) << 4)));
            }
            #pragma unroll
            for (int n = 0; n < 2; n++) {
                int r = w * 32 + n * 16 + (lane & 15);
                bfr[n] = *(const short8*)(Bb + r * 128 + (cb ^ ((r & 7) << 4)));
            }
            #pragma unroll
            for (int m = 0; m < 4; m++)
                #pragma unroll
                for (int n = 0; n < 2; n++)
                    acc[m][n] = __builtin_amdgcn_mfma_f32_16x16x32_bf16(af[m], bfr[n], acc[m][n], 0, 0, 0);
        }
        __syncthreads();
        cur ^= 1;
    }

    #pragma unroll
    for (int m = 0; m < 4; m++) {
        int rbase = row0 + m * 16 + ((lane >> 4) << 2);
        #pragma unroll
        for (int n = 0; n < 2; n++) {
            int col = col0 + w * 32 + n * 16 + (lane & 15);
            float bval = bias[col];
            #pragma unroll
            for (int j = 0; j < 4; j++) {
                float v = acc[m][n][j] + bval + bf2f(residb[(size_t)(rbase + j) * N + col]);
                Cb[(size_t)(rbase + j) * N + col] = f2bf(v);
            }
        }
    }
}

// ---------------- fused ProbSparse attention (one block per (bc,h)) ----------------
__global__ __launch_bounds__(256, 2) void attn_fused(const short* __restrict__ qkvb,
                                                     const int* __restrict__ samp,
                                                     short* __restrict__ ctxb) {
    __shared__ float Sbuf[64 * 130];   // 33.28 KB; overlays Stop[32*130] + Pb
    __shared__ short Vt[64 * 128];     // 16 KB, XOR-swizzled rows of 256 B
    __shared__ short Kls[128 * 64];    // 16 KB, XOR-swizzled rows of 128 B
    __shared__ float Mv[128];
    __shared__ int   topl[32];
    __shared__ float vmean[64];
    __shared__ float vpart[256];

    float* Stop = Sbuf;                          // 32 x 130 fp32
    short* Pb   = (short*)(Sbuf + 32 * 130);     // 32 x 128 bf16, XOR-swizzled

    int bh = blockIdx.x, bc = bh >> 3, h = bh & 7;
    int tid = threadIdx.x, w = tid >> 6, lane = tid & 63;
    const short* base = qkvb + (size_t)bc * NP * 1536 + h * DH;
    short* cbase = ctxb + (size_t)bc * NP * DM + h * DH;

    // P0: stage K (swizzled rows) + V transposed (swizzled)
    for (int e = tid; e < 1024; e += 256) {
        int row = e >> 3, c8 = e & 7;
        short8 kv = *(const short8*)(base + (size_t)row * 1536 + 512 + c8 * 8);
        *(short8*)((char*)Kls + row * 128 + ((c8 * 16) ^ ((row & 7) << 4))) = kv;
        short8 vv = *(const short8*)(base + (size_t)row * 1536 + 1024 + c8 * 8);
        #pragma unroll
        for (int j = 0; j < 8; j++) {
            int d = c8 * 8 + j;
            *(short*)((char*)Vt + d * 256 + ((2 * row) ^ ((d & 7) << 4))) = vv[j];
        }
    }
    __syncthreads();
    {
        int d = tid & 63, part = tid >> 6;
        float s = 0.f;
        #pragma unroll
        for (int i4 = 0; i4 < 4; i4++) {
            short8 v = *(const short8*)((char*)Vt + d * 256 + ((part * 64 + i4 * 16) ^ ((d & 7) << 4)));
            #pragma unroll
            for (int j = 0; j < 8; j++) s += bf2f(v[j]);
        }
        vpart[part * 64 + d] = s;
    }

    // P2: S halves (64 rows each) + M-score gather per half
    for (int half = 0; half < 2; half++) {
        int ar = half * 64 + 16 * w + (lane & 15);
        const short* qp = base + (size_t)ar * 1536;
        short8 a0 = *(const short8*)(qp + (lane >> 4) * 8);
        short8 a1 = *(const short8*)(qp + 32 + (lane >> 4) * 8);
        #pragma unroll 2
        for (int ct = 0; ct < 8; ct++) {
            int br = ct * 16 + (lane & 15);
            int cb0 = (lane >> 4) * 16;
            short8 b0 = *(const short8*)((char*)Kls + br * 128 + (cb0 ^ ((br & 7) << 4)));
            short8 b1 = *(const short8*)((char*)Kls + br * 128 + ((cb0 + 64) ^ ((br & 7) << 4)));
            f32x4 acc = {};
            acc = __builtin_amdgcn_mfma_f32_16x16x32_bf16(a0, b0, acc, 0, 0, 0);
            acc = __builtin_amdgcn_mfma_f32_16x16x32_bf16(a1, b1, acc, 0, 0, 0);
            int r0 = 16 * w + ((lane >> 4) << 2);
            int c = ct * 16 + (lane & 15);
            #pragma unroll
            for (int j = 0; j < 4; j++) Sbuf[(r0 + j) * 130 + c] = acc[j] * 0.125f;
        }
        __syncthreads();
        if (tid < 64) {
            int r = half * 64 + tid;
            const int* sp = samp + r * U;
            const float* Srow = &Sbuf[tid * 130];
            float mx = -1e30f, sm = 0.f;
            #pragma unroll
            for (int s = 0; s < U; s++) { float v = Srow[sp[s]]; mx = fmaxf(mx, v); sm += v; }
            Mv[r] = mx - sm * (1.0f / U);
        } else if (half == 0 && tid < 128) {
            int d = tid - 64;
            vmean[d] = (vpart[d] + vpart[64 + d] + vpart[128 + d] + vpart[192 + d]) * (1.0f / 128.0f);
        }
        __syncthreads();
    }

    // P6: wave0 = top-25 shuffle argmax; waves 1-3 = broadcast vmean to ALL ctx rows
    if (w == 0) {
        float v0 = Mv[lane], v1 = Mv[lane + 64];
        for (int it = 0; it < U; it++) {
            float bv; int bi;
            if (v1 > v0) { bv = v1; bi = lane + 64; } else { bv = v0; bi = lane; }
            #pragma unroll
            for (int o = 32; o > 0; o >>= 1) {
                float ov = __shfl_xor(bv, o);
                int   oi = __shfl_xor(bi, o);
                if (ov > bv || (ov == bv && oi < bi)) { bv = ov; bi = oi; }
            }
            if (lane == 0) topl[it] = bi;
            if (bi == lane) v0 = -1e30f;
            if (bi == lane + 64) v1 = -1e30f;
        }
    } else {
        for (int e = tid - 64; e < 128 * 16; e += 192) {
            int n = e >> 4, c4 = e & 15;
            short4 o;
            o.x = f2bf(vmean[c4 * 4 + 0]); o.y = f2bf(vmean[c4 * 4 + 1]);
            o.z = f2bf(vmean[c4 * 4 + 2]); o.w = f2bf(vmean[c4 * 4 + 3]);
            *(short4*)(cbase + (size_t)n * DM + c4 * 4) = o;
        }
    }
    __syncthreads();

    // P7: recompute scores for the 25 top rows into Stop
    {
        int rt = w & 1, cth = w >> 1;
        int u = rt * 16 + (lane & 15);
        int qrow = topl[u < U ? u : U - 1];
        const short* qp = base + (size_t)qrow * 1536;
        short8 a0 = *(const short8*)(qp + (lane >> 4) * 8);
        short8 a1 = *(const short8*)(qp + 32 + (lane >> 4) * 8);
        #pragma unroll
        for (int cti = 0; cti < 4; cti++) {
            int ct = cth * 4 + cti;
            int br = ct * 16 + (lane & 15);
            int cb0 = (lane >> 4) * 16;
            short8 b0 = *(const short8*)((char*)Kls + br * 128 + (cb0 ^ ((br & 7) << 4)));
            short8 b1 = *(const short8*)((char*)Kls + br * 128 + ((cb0 + 64) ^ ((br & 7) << 4)));
            f32x4 acc = {};
            acc = __builtin_amdgcn_mfma_f32_16x16x32_bf16(a0, b0, acc, 0, 0, 0);
            acc = __builtin_amdgcn_mfma_f32_16x16x32_bf16(a1, b1, acc, 0, 0, 0);
            int r0 = rt * 16 + ((lane >> 4) << 2);
            int c = ct * 16 + (lane & 15);
            #pragma unroll
            for (int j = 0; j < 4; j++) Stop[(r0 + j) * 130 + c] = acc[j] * 0.125f;
        }
    }
    __syncthreads();

    // P8: softmax of top rows -> Pb (bf16, swizzled); zero pad rows 25..31
    for (int e = tid; e < 7 * 128; e += 256)
        Pb[(25 + (e >> 7)) * 128 + (e & 127)] = 0;
    for (int it = w; it < U; it += 4) {
        float s0 = Stop[it * 130 + lane], s1 = Stop[it * 130 + 64 + lane];
        float mx = fmaxf(s0, s1);
        #pragma unroll
        for (int o = 32; o > 0; o >>= 1) mx = fmaxf(mx, __shfl_xor(mx, o));
        float e0 = expf(s0 - mx), e1 = expf(s1 - mx);
        float sum = e0 + e1;
        #pragma unroll
        for (int o = 32; o > 0; o >>= 1) sum += __shfl_xor(sum, o);
        float inv = 1.0f / sum;
        int sw = (it & 7) << 4;
        *(short*)((char*)Pb + it * 256 + ((2 * lane) ^ sw))        = f2bf(e0 * inv);
        *(short*)((char*)Pb + it * 256 + ((2 * (64 + lane)) ^ sw)) = f2bf(e1 * inv);
    }
    __syncthreads();

    // P9: PV via MFMA, scatter to top rows
    #pragma unroll
    for (int t = w * 2; t < w * 2 + 2; t++) {
        int rt = t >> 2, ct = t & 3;
        int pr = rt * 16 + (lane & 15);
        int vr = ct * 16 + (lane & 15);
        f32x4 acc = {};
        #pragma unroll
        for (int ks = 0; ks < 4; ks++) {
            int off = ks * 64 + (lane >> 4) * 16;
            short8 a = *(const short8*)((char*)Pb + pr * 256 + (off ^ ((pr & 7) << 4)));
            short8 b = *(const short8*)((char*)Vt + vr * 256 + (off ^ ((vr & 7) << 4)));
            acc = __builtin_amdgcn_mfma_f32_16x16x32_bf16(a, b, acc, 0, 0, 0);
        }
        int u0 = rt * 16 + ((lane >> 4) << 2), d = ct * 16 + (lane & 15);
        #pragma unroll
        for (int j = 0; j < 4; j++) {
            int u = u0 + j;
            if (u < U) cbase[(size_t)topl[u] * DM + d] = f2bf(acc[j]);
        }
    }
}

// ---------------- LayerNorm: bf16 in (residual pre-folded), bf16 out ----------------
__global__ __launch_bounds__(256) void residual_ln(const short* __restrict__ a,
                                                   const float* __restrict__ g,
                                                   const float* __restrict__ beta,
                                                   short* __restrict__ outb) {
    int row = blockIdx.x;
    int tid = threadIdx.x;
    uint32_t va = ((const uint32_t*)(a + (size_t)row * DM))[tid];
    float x0 = bf2f((short)(va & 0xffff));
    float x1 = bf2f((short)(va >> 16));
    __shared__ float rs[256], rss[256];
    rs[tid] = x0 + x1; rss[tid] = x0 * x0 + x1 * x1; __syncthreads();
    for (int o = 128; o > 0; o >>= 1) {
        if (tid < o) { rs[tid] += rs[tid + o]; rss[tid] += rss[tid + o]; }
        __syncthreads();
    }
    float m = rs[0] / DM;
    float var = rss[0] / DM - m * m;
    float r = rsqrtf(var + 1e-5f);
    float2 gg = ((const float2*)g)[tid];
    float2 bb = ((const float2*)beta)[tid];
    float y0 = (x0 - m) * r * gg.x + bb.x;
    float y1 = (x1 - m) * r * gg.y + bb.y;
    uint32_t vo = (uint32_t)(uint16_t)f2bf(y0) | ((uint32_t)(uint16_t)f2bf(y1) << 16);
    ((uint32_t*)(outb + (size_t)row * DM))[tid] = vo;
}

// ---------------- transpose tokb(bc,p,d) bf16 -> featb(bc,d,p) bf16 ----------------
__global__ void transpose_tok(const short* __restrict__ tokb, short* __restrict__ featb) {
    __shared__ short t[32][34];
    int bc = blockIdx.z, dt = blockIdx.y, pt = blockIdx.x;
    int tx = threadIdx.x, ty = threadIdx.y;
    #pragma unroll
    for (int i = 0; i < 4; i++) {
        int p = pt * 32 + ty + i * 8;
        int d = dt * 32 + tx;
        t[ty + i * 8][tx] = tokb[((size_t)bc * NP + p) * DM + d];
    }
    __syncthreads();
    #pragma unroll
    for (int i = 0; i < 4; i++) {
        int d = dt * 32 + ty + i * 8;
        int p = pt * 32 + tx;
        featb[(size_t)bc * (DM * NP) + (size_t)d * NP + p] = t[tx][ty + i * 8];
    }
}

// ---------------- head MFMA split-K: partial[blk][96][64] ----------------
__global__ __launch_bounds__(256) void head_mfma(const float* __restrict__ hw,
                                                 const short* __restrict__ featb,
                                                 float* __restrict__ partial) {
    __shared__ short Als[96 * 64];
    __shared__ short Bls[64 * 64];
    int tid = threadIdx.x;
    int w = tid >> 6, lane = tid & 63;
    int wm = w >> 1, wn = w & 1;
    int kb = blockIdx.x * HKB;
    f32x4 acc[3][2] = {};
    const char* Ab = (const char*)Als;
    const char* Bb = (const char*)Bls;

    for (int kt = 0; kt < HKB; kt += 64) {
        #pragma unroll
        for (int i = 0; i < 6; i++) {
            int s = tid + i * 256;
            int row = s >> 4, c4 = s & 15;
            float4 v = *(const float4*)(hw + (size_t)row * 65536 + kb + kt + c4 * 4);
            short4 o; o.x = f2bf(v.x); o.y = f2bf(v.y); o.z = f2bf(v.z); o.w = f2bf(v.w);
            int boff = row * 128 + ((c4 * 8) ^ ((row & 7) << 4));
            *(short4*)((char*)Als + boff) = o;
        }
        #pragma unroll
        for (int i = 0; i < 4; i++) {
            int s = tid + i * 256;
            int row = s >> 4, c4 = s & 15;
            short4 o;
            if (row < BC) o = *(const short4*)(featb + (size_t)row * 65536 + kb + kt + c4 * 4);
            else { o.x = 0; o.y = 0; o.z = 0; o.w = 0; }
            int boff = row * 128 + ((c4 * 8) ^ ((row & 7) << 4));
            *(short4*)((char*)Bls + boff) = o;
        }
        __syncthreads();
        #pragma unroll
        for (int ks = 0; ks < 2; ks++) {
            int cb = ks * 64 + ((lane >> 4) << 4);
            short8 af[3], bfr[2];
            #pragma unroll
            for (int m = 0; m < 3; m++) {
                int r = wm * 48 + m * 16 + (lane & 15);
                af[m] = *(const short8*)(Ab + r * 128 + (cb ^ ((r & 7) << 4)));
            }
            #pragma unroll
            for (int n = 0; n < 2; n++) {
                int r = wn * 32 + n * 16 + (lane & 15);
                bfr[n] = *(const short8*)(Bb + r * 128 + (cb ^ ((r & 7) << 4)));
            }
            #pragma unroll
            for (int m = 0; m < 3; m++)
                #pragma unroll
                for (int n = 0; n < 2; n++)
                    acc[m][n] = __builtin_amdgcn_mfma_f32_16x16x32_bf16(af[m], bfr[n], acc[m][n], 0, 0, 0);
        }
        __syncthreads();
    }

    float* pb = partial + (size_t)blockIdx.x * (96 * 64);
    #pragma unroll
    for (int m = 0; m < 3; m++) {
        int rbase = wm * 48 + m * 16 + ((lane >> 4) << 2);
        #pragma unroll
        for (int n = 0; n < 2; n++) {
            int col = wn * 32 + n * 16 + (lane & 15);
            #pragma unroll
            for (int j = 0; j < 4; j++)
                pb[(rbase + j) * 64 + col] = acc[m][n][j];
        }
    }
}

// ---------------- finalize: 2-stage split-K reduction + bias + de-norm ----------------
__global__ void finalize_a(const float* __restrict__ partial, float* __restrict__ p2) {
    int i = blockIdx.x * 256 + threadIdx.x;   // 0..6143
    int s = blockIdx.y;                        // 0..7
    const float* p = partial + (size_t)s * 32 * 6144 + i;
    float sum = 0.f;
    #pragma unroll
    for (int b = 0; b < 32; b++) sum += p[(size_t)b * 6144];
    p2[s * 6144 + i] = sum;
}

__global__ void finalize_b(const float* __restrict__ p2, const float* __restrict__ hb,
                           const float* __restrict__ mean, const float* __restrict__ stdv,
                           float* __restrict__ out) {
    int i = blockIdx.x * 256 + threadIdx.x;
    if (i >= NB * 96 * CIN) return;
    int b = i / (96 * CIN);
    int r = i % (96 * CIN);
    int t = r / CIN, c = r % CIN;
    int bc = b * CIN + c;
    int j = t * 64 + bc;
    float s = 0.f;
    #pragma unroll
    for (int k = 0; k < 8; k++) s += p2[k * 6144 + j];
    out[i] = (s + hb[t]) * stdv[bc] + mean[bc];
}

// ---------------- launch ----------------
extern "C" void kernel_launch(void* const* d_in, const int* in_sizes, int n_in,
                              void* d_out, int out_size, void* d_ws, size_t ws_size,
                              hipStream_t stream) {
    (void)in_sizes; (void)n_in; (void)out_size; (void)ws_size;
    const float* x_enc   = (const float*)d_in[0];
    const float* patch_W = (const float*)d_in[4];
    const float* Wq  = (const float*)d_in[5];
    const float* bq  = (const float*)d_in[6];
    const float* Wk  = (const float*)d_in[7];
    const float* bk  = (const float*)d_in[8];
    const float* Wv  = (const float*)d_in[9];
    const float* bv  = (const float*)d_in[10];
    const float* Wo  = (const float*)d_in[11];
    const float* bo  = (const float*)d_in[12];
    const float* c1W = (const float*)d_in[13];
    const float* c1b = (const float*)d_in[14];
    const float* c2W = (const float*)d_in[15];
    const float* c2b = (const float*)d_in[16];
    const float* ln1g = (const float*)d_in[17];
    const float* ln1b = (const float*)d_in[18];
    const float* ln2g = (const float*)d_in[19];
    const float* ln2b = (const float*)d_in[20];
    const float* encg = (const float*)d_in[21];
    const float* encb = (const float*)d_in[22];
    const float* headW = (const float*)d_in[23];
    const float* headb = (const float*)d_in[24];
    float* out = (float*)d_out;

    float* ws = (float*)d_ws;
    float* mean = ws + 0;
    float* stdv = ws + 64;
    float* bqkv = ws + 128;                 // 2*1536 floats
    int*   samp = (int*)(ws + 6144);        // 6400 ints
    size_t off = 32768;
    const size_t T = (size_t)NTOK * DM;     // 3,670,016
    float* partial = ws + off; off += T;      // head split-K partials (256*6144)
    float* p2      = ws + off; off += 65536;
    // bf16 region
    short* sbase = (short*)(ws + off);
    size_t soff = 0;
    short* tok_b  = sbase + soff; soff += T;
    short* ctx_b  = sbase + soff; soff += T;
    short* x1_b   = sbase + soff; soff += T;
    short* pA_b   = sbase + soff; soff += T;
    short* qkv_b  = sbase + soff; soff += 3 * T;            // bf16 QKV
    short* ffn_b  = sbase + soff; soff += (size_t)NTOK * DFF;
    short* featb  = ffn_b;                  // reuse: ffn_b dead after encoder loop
    short* wqkv_b = sbase + soff; soff += 2 * 1536 * DM;
    short* wo_b   = sbase + soff; soff += 2 * DM * DM;
    short* c1w_b  = sbase + soff; soff += 2 * (size_t)DFF * DM;
    short* c2w_b  = sbase + soff; soff += 2 * (size_t)DM * DFF;

    stats_kernel<<<BC, 256, 0, stream>>>(x_enc, mean, stdv);
    prep_weights<<<6146, 256, 0, stream>>>(Wq, Wk, Wv, bq, bk, bv, Wo, c1W, c2W,
                                           wqkv_b, bqkv, wo_b, c1w_b, c2w_b, samp);
    patch_embed<<<dim3(NP, BC), 128, 0, stream>>>(x_enc, patch_W, mean, stdv, tok_b);

    for (int l = 0; l < 2; l++) {
        // QKV (bf16 out)
        gemm_mfma<0><<<dim3(56, 12), 256, 0, stream>>>(tok_b, wqkv_b + (size_t)l * 1536 * DM, bqkv + l * 1536, qkv_b, NTOK, 1536, DM);
        attn_fused<<<448, 256, 0, stream>>>(qkv_b, samp + l * 3200, ctx_b);
        // Wo + residual(tok_b) folded -> pA_b; then LN1 -> x1_b
        gemm_mfma64<<<dim3(112, 4), 256, 0, stream>>>(ctx_b, wo_b + (size_t)l * DM * DM, bo + l * DM, tok_b, pA_b, NTOK, DM, DM);
        residual_ln<<<NTOK, 256, 0, stream>>>(pA_b, ln1g + l * DM, ln1b + l * DM, x1_b);
        gemm_mfma<1><<<dim3(56, 16), 256, 0, stream>>>(x1_b, c1w_b + (size_t)l * DFF * DM, c1b + l * DFF, ffn_b, NTOK, DFF, DM);
        // FFN2 + residual(x1_b) folded -> pA_b; then LN2 -> tok_b
        gemm_mfma64<<<dim3(112, 4), 256, 0, stream>>>(ffn_b, c2w_b + (size_t)l * DM * DFF, c2b + l * DM, x1_b, pA_b, NTOK, DM, DFF);
        residual_ln<<<NTOK, 256, 0, stream>>>(pA_b, ln2g + l * DM, ln2b + l * DM, tok_b);
    }

    // final encoder LN -> x1_b (bf16)
    residual_ln<<<NTOK, 256, 0, stream>>>(tok_b, encg, encb, x1_b);
    transpose_tok<<<dim3(4, 16, BC), dim3(32, 8), 0, stream>>>(x1_b, featb);
    head_mfma<<<HNB, 256, 0, stream>>>(headW, featb, partial);
    finalize_a<<<dim3(24, 8), 256, 0, stream>>>(partial, p2);
    finalize_b<<<21, 256, 0, stream>>>(p2, headb, mean, stdv, out);
}

// Round 12
// 300.635 us; speedup vs baseline: 1.4082x; 1.0289x over previous
//
#include <hip/hip_runtime.h>
#include <math.h>
#include <stdint.h>

#define SEQ   1024
#define CIN   7
#define NB    8
#define BC    56          // NB*CIN
#define NP    128         // patches
#define DM    512
#define NH    8
#define DH    64
#define DFF   2048
#define U     25
#define NTOK  (BC*NP)     // 7168
#define PE_COEF (-9.210340371976184f / 512.0f)  // -ln(10000)/DM
#define HKB   256         // head: K elems per split-K block
#define HNB   256         // head: number of split-K blocks (HKB*HNB = 65536)

typedef __attribute__((ext_vector_type(8))) short short8;
typedef __attribute__((ext_vector_type(4))) float f32x4;

__device__ __forceinline__ short f2bf(float x) {
    union { float f; uint32_t u; } v; v.f = x;
    uint32_t r = v.u + 0x7FFFu + ((v.u >> 16) & 1u);
    return (short)(r >> 16);
}
__device__ __forceinline__ float bf2f(short x) {
    union { uint32_t u; float f; } v; v.u = ((uint32_t)(uint16_t)x) << 16;
    return v.f;
}

__device__ __forceinline__ void gl_lds16(const void* g, void* s) {
    __builtin_amdgcn_global_load_lds((const __attribute__((address_space(1))) void*)g,
                                     (__attribute__((address_space(3))) void*)s, 16, 0, 0);
}

// ---------------- threefry2x32-20 (JAX PRNG) ----------------
__device__ __forceinline__ void tf_round(uint32_t& x0, uint32_t& x1, uint32_t r) {
    x0 += x1; x1 = (x1 << r) | (x1 >> (32u - r)); x1 ^= x0;
}
__device__ void threefry2x32(uint32_t k0, uint32_t k1, uint32_t x0, uint32_t x1,
                             uint32_t& o0, uint32_t& o1) {
    uint32_t ks[3] = { k0, k1, k0 ^ k1 ^ 0x1BD11BDAu };
    x0 += ks[0]; x1 += ks[1];
    const uint32_t rotA[4] = {13u, 15u, 26u, 6u}, rotB[4] = {17u, 29u, 16u, 24u};
    #pragma unroll
    for (int i = 0; i < 5; i++) {
        const uint32_t* rr = (i & 1) ? rotB : rotA;
        tf_round(x0, x1, rr[0]); tf_round(x0, x1, rr[1]);
        tf_round(x0, x1, rr[2]); tf_round(x0, x1, rr[3]);
        x0 += ks[(i + 1) % 3];
        x1 += ks[(i + 2) % 3] + (uint32_t)(i + 1);
    }
    o0 = x0; o1 = x1;
}

// ---------------- fused prep: pack QKV weights, convert Wo/c1W/c2W, samp, stats ----------------
__global__ void prep_weights(const float* __restrict__ Wq, const float* __restrict__ Wk,
                             const float* __restrict__ Wv, const float* __restrict__ bq,
                             const float* __restrict__ bk, const float* __restrict__ bv,
                             const float* __restrict__ Wo, const float* __restrict__ c1W,
                             const float* __restrict__ c2W, const float* __restrict__ x_enc,
                             short* __restrict__ wqkv, float* __restrict__ bqkv,
                             short* __restrict__ wo_b, short* __restrict__ c1w_b,
                             short* __restrict__ c2w_b, int* __restrict__ samp,
                             float* __restrict__ mean, float* __restrict__ stdv) {
    int blk = blockIdx.x, tid = threadIdx.x;
    if (blk < 1536) {                       // pack_qkv: 2*1536*128 float4 slots
        int idx = blk * 256 + tid;
        int k4 = idx & 127;
        int n  = (idx >> 7) % 1536;
        int l  = idx / (1536 * 128);
        int sel3 = n >> 9;
        int nn = n & 511;
        const float* src = sel3 == 0 ? Wq : sel3 == 1 ? Wk : Wv;
        float4 v = *(const float4*)(src + ((size_t)l * DM + nn) * DM + k4 * 4);
        short4 o; o.x = f2bf(v.x); o.y = f2bf(v.y); o.z = f2bf(v.z); o.w = f2bf(v.w);
        *(short4*)(wqkv + ((size_t)l * 1536 + n) * DM + k4 * 4) = o;
        if (k4 == 0) {
            const float* bsrc = sel3 == 0 ? bq : sel3 == 1 ? bk : bv;
            bqkv[l * 1536 + n] = bsrc[l * DM + nn];
        }
    } else if (blk < 6144) {                // converts
        const float* in; short* out; int i;
        if (blk < 2048)      { in = Wo;  out = wo_b;  i = (blk - 1536) * 256 + tid; }
        else if (blk < 4096) { in = c1W; out = c1w_b; i = (blk - 2048) * 256 + tid; }
        else                 { in = c2W; out = c2w_b; i = (blk - 4096) * 256 + tid; }
        float4 v = ((const float4*)in)[i];
        short4 o; o.x = f2bf(v.x); o.y = f2bf(v.y); o.z = f2bf(v.z); o.w = f2bf(v.w);
        ((short4*)out)[i] = o;
    } else if (blk < 6146) {                // samp: 2 blocks
        int l = blk - 6144;
        uint32_t s0, s1; threefry2x32(0u, 42u, 0u, (uint32_t)l, s0, s1);
        uint32_t a0, a1, b0, b1;
        threefry2x32(s0, s1, 0u, 2u, a0, a1);
        threefry2x32(s0, s1, 1u, 3u, b0, b1);
        uint32_t k20 = a1, k21 = b1;
        for (int i = tid; i < 1600; i += 256) {
            uint32_t o0, o1;
            threefry2x32(k20, k21, (uint32_t)i, (uint32_t)(1600 + i), o0, o1);
            samp[l * 3200 + i]        = (int)(o0 & 127u);
            samp[l * 3200 + 1600 + i] = (int)(o1 & 127u);
        }
    } else {                                 // stats: 56 blocks, one per (b,c)
        int bc = blk - 6146;
        int b = bc / CIN, c = bc % CIN;
        const float* base = x_enc + (size_t)b * SEQ * CIN + c;
        float s = 0.f, ss = 0.f;
        for (int i = tid; i < SEQ; i += 256) {
            float v = base[(size_t)i * CIN];
            s += v; ss += v * v;
        }
        __shared__ float rs[256], rss[256];
        rs[tid] = s; rss[tid] = ss; __syncthreads();
        for (int o = 128; o > 0; o >>= 1) {
            if (tid < o) { rs[tid] += rs[tid + o]; rss[tid] += rss[tid + o]; }
            __syncthreads();
        }
        if (tid == 0) {
            float m = rs[0] / SEQ;
            float v = rss[0] / SEQ - m * m;
            mean[bc] = m;
            stdv[bc] = sqrtf(v + 1e-5f);
        }
    }
}

// ---------------- patch embedding + sinusoidal PE (bf16 out) ----------------
__global__ void patch_embed(const float* __restrict__ x, const float* __restrict__ pw,
                            const float* __restrict__ mean, const float* __restrict__ stdv,
                            short* __restrict__ tokb) {
    int p = blockIdx.x, bc = blockIdx.y;
    int b = bc / CIN, c = bc % CIN;
    __shared__ float xs[16];
    if (threadIdx.x < 16) {
        int i = p * 8 + threadIdx.x;
        if (i > SEQ - 1) i = SEQ - 1;   // edge pad
        xs[threadIdx.x] = (x[(size_t)b * SEQ * CIN + (size_t)i * CIN + c] - mean[bc]) / stdv[bc];
    }
    __syncthreads();
    for (int d = threadIdx.x; d < DM; d += blockDim.x) {
        float acc = 0.f;
        const float* wr = pw + d * 16;
        #pragma unroll
        for (int t = 0; t < 16; t++) acc += xs[t] * wr[t];
        int k2 = d & ~1;
        float ang = (float)p * __expf((float)k2 * PE_COEF);
        acc += (d & 1) ? __cosf(ang) : __sinf(ang);
        tokb[((size_t)bc * NP + p) * DM + d] = f2bf(acc);
    }
}

// ---------------- MFMA GEMM 128x128, 2-phase double-buffered pipeline ----------------
template<int ACT>   // ACT: 0 none, 1 fast GELU; bf16 out
__global__ __launch_bounds__(256) void gemm_mfma(const short* __restrict__ A,
                                                 const short* __restrict__ W,
                                                 const float* __restrict__ bias,
                                                 short* __restrict__ Cb,
                                                 int M, int N, int K) {
    __shared__ short LDSU[2][16384];   // [buf][ A:0..8191 | B:8192..16383 ]  64 KB
    int tid = threadIdx.x;
    int w = tid >> 6, lane = tid & 63;
    int row0 = blockIdx.x * 128, col0 = blockIdx.y * 128;
    int wrow = (w >> 1) * 64, wcol = (w & 1) * 64;
    int nt = K >> 6;
    f32x4 acc[4][4] = {};

    auto stage = [&](int b, int kt) {
        #pragma unroll
        for (int i = 0; i < 4; i++) {
            int L = i * 4096 + w * 1024 + lane * 16;    // linear LDS byte offset
            int row = L >> 7;
            int cb  = L & 127;
            int scb = cb ^ ((row & 7) << 4);             // inverse-swizzled source col
            gl_lds16(A + (size_t)(row0 + row) * K + kt + (scb >> 1),
                     (char*)&LDSU[b][0] + i * 4096 + w * 1024);
            gl_lds16(W + (size_t)(col0 + row) * K + kt + (scb >> 1),
                     (char*)&LDSU[b][8192] + i * 4096 + w * 1024);
        }
    };

    stage(0, 0);
    __syncthreads();
    int cur = 0;
    for (int t = 0; t < nt; t++) {
        if (t + 1 < nt) stage(cur ^ 1, (t + 1) * 64);   // prefetch under compute
        const char* Ab = (const char*)&LDSU[cur][0];
        const char* Bb = (const char*)&LDSU[cur][8192];
        #pragma unroll
        for (int ks = 0; ks < 2; ks++) {
            int cb = ks * 64 + ((lane >> 4) << 4);
            short8 af[4], bfr[4];
            #pragma unroll
            for (int m = 0; m < 4; m++) {
                int r = wrow + m * 16 + (lane & 15);
                af[m] = *(const short8*)(Ab + r * 128 + (cb ^ ((r & 7) << 4)));
            }
            #pragma unroll
            for (int n = 0; n < 4; n++) {
                int r = wcol + n * 16 + (lane & 15);
                bfr[n] = *(const short8*)(Bb + r * 128 + (cb ^ ((r & 7) << 4)));
            }
            #pragma unroll
            for (int m = 0; m < 4; m++)
                #pragma unroll
                for (int n = 0; n < 4; n++)
                    acc[m][n] = __builtin_amdgcn_mfma_f32_16x16x32_bf16(af[m], bfr[n], acc[m][n], 0, 0, 0);
        }
        __syncthreads();
        cur ^= 1;
    }

    #pragma unroll
    for (int m = 0; m < 4; m++) {
        int rbase = row0 + wrow + m * 16 + ((lane >> 4) << 2);
        #pragma unroll
        for (int n = 0; n < 4; n++) {
            int col = col0 + wcol + n * 16 + (lane & 15);
            float bval = bias[col];
            #pragma unroll
            for (int j = 0; j < 4; j++) {
                float v = acc[m][n][j] + bval;
                if (ACT == 1) {
                    float u = 0.7978845608f * (v + 0.044715f * v * v * v);
                    float e = exp2f(2.8853900817779268f * u);
                    v = v - v / (e + 1.0f);
                }
                Cb[(size_t)(rbase + j) * N + col] = f2bf(v);
            }
        }
    }
}

// ---------------- MFMA GEMM 64x128 tile + bf16 residual add, bf16 out ----------------
__global__ __launch_bounds__(256) void gemm_mfma64(const short* __restrict__ A,
                                                   const short* __restrict__ W,
                                                   const float* __restrict__ bias,
                                                   const short* __restrict__ residb,
                                                   short* __restrict__ Cb,
                                                   int M, int N, int K) {
    __shared__ short LDSU[2][12288];   // [buf][ A:0..4095 sh | B:4096..12287 sh ] 48 KB
    int tid = threadIdx.x;
    int w = tid >> 6, lane = tid & 63;
    int row0 = blockIdx.x * 64, col0 = blockIdx.y * 128;
    int nt = K >> 6;
    f32x4 acc[4][2] = {};

    auto stage = [&](int b, int kt) {
        #pragma unroll
        for (int i = 0; i < 2; i++) {
            int L = (i * 4 + w) * 1024 + lane * 16;
            int row = L >> 7, cb = L & 127;
            int scb = cb ^ ((row & 7) << 4);
            gl_lds16(A + (size_t)(row0 + row) * K + kt + (scb >> 1),
                     (char*)&LDSU[b][0] + (i * 4 + w) * 1024);
        }
        #pragma unroll
        for (int i = 0; i < 4; i++) {
            int L = (i * 4 + w) * 1024 + lane * 16;
            int row = L >> 7, cb = L & 127;
            int scb = cb ^ ((row & 7) << 4);
            gl_lds16(W + (size_t)(col0 + row) * K + kt + (scb >> 1),
                     (char*)&LDSU[b][4096] + (i * 4 + w) * 1024);
        }
    };

    stage(0, 0);
    __syncthreads();
    int cur = 0;
    for (int t = 0; t < nt; t++) {
        if (t + 1 < nt) stage(cur ^ 1, (t + 1) * 64);
        const char* Ab = (const char*)&LDSU[cur][0];
        const char* Bb = (const char*)&LDSU[cur][4096];
        #pragma unroll
        for (int ks = 0; ks < 2; ks++) {
            int cb = ks * 64 + ((lane >> 4) << 4);
            short8 af[4], bfr[2];
            #pragma unroll
            for (int m = 0; m < 4; m++) {
                int r = m * 16 + (lane & 15);
                af[m] = *(const short8*)(Ab + r * 128 + (cb ^ ((r & 7) << 4)));
            }
            #pragma unroll
            for (int n = 0; n < 2; n++) {
                int r = w * 32 + n * 16 + (lane & 15);
                bfr[n] = *(const short8*)(Bb + r * 128 + (cb ^ ((r & 7) << 4)));
            }
            #pragma unroll
            for (int m = 0; m < 4; m++)
                #pragma unroll
                for (int n = 0; n < 2; n++)
                    acc[m][n] = __builtin_amdgcn_mfma_f32_16x16x32_bf16(af[m], bfr[n], acc[m][n], 0, 0, 0);
        }
        __syncthreads();
        cur ^= 1;
    }

    #pragma unroll
    for (int m = 0; m < 4; m++) {
        int rbase = row0 + m * 16 + ((lane >> 4) << 2);
        #pragma unroll
        for (int n = 0; n < 2; n++) {
            int col = col0 + w * 32 + n * 16 + (lane & 15);
            float bval = bias[col];
            #pragma unroll
            for (int j = 0; j < 4; j++) {
                float v = acc[m][n][j] + bval + bf2f(residb[(size_t)(rbase + j) * N + col]);
                Cb[(size_t)(rbase + j) * N + col] = f2bf(v);
            }
        }
    }
}

// ---------------- fused ProbSparse attention (one block per (bc,h)) ----------------
__global__ __launch_bounds__(256, 2) void attn_fused(const short* __restrict__ qkvb,
                                                     const int* __restrict__ samp,
                                                     short* __restrict__ ctxb) {
    __shared__ float Sbuf[64 * 130];   // 33.28 KB; overlays Stop[32*130] + Pb
    __shared__ short Vt[64 * 128];     // 16 KB, XOR-swizzled rows of 256 B
    __shared__ short Kls[128 * 64];    // 16 KB, XOR-swizzled rows of 128 B
    __shared__ float Mv[128];
    __shared__ int   topl[32];
    __shared__ float vmean[64];
    __shared__ float vpart[256];

    float* Stop = Sbuf;                          // 32 x 130 fp32
    short* Pb   = (short*)(Sbuf + 32 * 130);     // 32 x 128 bf16, XOR-swizzled

    int bh = blockIdx.x, bc = bh >> 3, h = bh & 7;
    int tid = threadIdx.x, w = tid >> 6, lane = tid & 63;
    const short* base = qkvb + (size_t)bc * NP * 1536 + h * DH;
    short* cbase = ctxb + (size_t)bc * NP * DM + h * DH;

    // P0: stage K (swizzled rows) + V transposed (swizzled)
    for (int e = tid; e < 1024; e += 256) {
        int row = e >> 3, c8 = e & 7;
        short8 kv = *(const short8*)(base + (size_t)row * 1536 + 512 + c8 * 8);
        *(short8*)((char*)Kls + row * 128 + ((c8 * 16) ^ ((row & 7) << 4))) = kv;
        short8 vv = *(const short8*)(base + (size_t)row * 1536 + 1024 + c8 * 8);
        #pragma unroll
        for (int j = 0; j < 8; j++) {
            int d = c8 * 8 + j;
            *(short*)((char*)Vt + d * 256 + ((2 * row) ^ ((d & 7) << 4))) = vv[j];
        }
    }
    __syncthreads();
    {
        int d = tid & 63, part = tid >> 6;
        float s = 0.f;
        #pragma unroll
        for (int i4 = 0; i4 < 4; i4++) {
            short8 v = *(const short8*)((char*)Vt + d * 256 + ((part * 64 + i4 * 16) ^ ((d & 7) << 4)));
            #pragma unroll
            for (int j = 0; j < 8; j++) s += bf2f(v[j]);
        }
        vpart[part * 64 + d] = s;
    }

    // P2: S halves (64 rows each) + M-score gather per half
    for (int half = 0; half < 2; half++) {
        int ar = half * 64 + 16 * w + (lane & 15);
        const short* qp = base + (size_t)ar * 1536;
        short8 a0 = *(const short8*)(qp + (lane >> 4) * 8);
        short8 a1 = *(const short8*)(qp + 32 + (lane >> 4) * 8);
        #pragma unroll 2
        for (int ct = 0; ct < 8; ct++) {
            int br = ct * 16 + (lane & 15);
            int cb0 = (lane >> 4) * 16;
            short8 b0 = *(const short8*)((char*)Kls + br * 128 + (cb0 ^ ((br & 7) << 4)));
            short8 b1 = *(const short8*)((char*)Kls + br * 128 + ((cb0 + 64) ^ ((br & 7) << 4)));
            f32x4 acc = {};
            acc = __builtin_amdgcn_mfma_f32_16x16x32_bf16(a0, b0, acc, 0, 0, 0);
            acc = __builtin_amdgcn_mfma_f32_16x16x32_bf16(a1, b1, acc, 0, 0, 0);
            int r0 = 16 * w + ((lane >> 4) << 2);
            int c = ct * 16 + (lane & 15);
            #pragma unroll
            for (int j = 0; j < 4; j++) Sbuf[(r0 + j) * 130 + c] = acc[j] * 0.125f;
        }
        __syncthreads();
        if (tid < 64) {
            int r = half * 64 + tid;
            const int* sp = samp + r * U;
            const float* Srow = &Sbuf[tid * 130];
            float mx = -1e30f, sm = 0.f;
            #pragma unroll
            for (int s = 0; s < U; s++) { float v = Srow[sp[s]]; mx = fmaxf(mx, v); sm += v; }
            Mv[r] = mx - sm * (1.0f / U);
        } else if (half == 0 && tid < 128) {
            int d = tid - 64;
            vmean[d] = (vpart[d] + vpart[64 + d] + vpart[128 + d] + vpart[192 + d]) * (1.0f / 128.0f);
        }
        __syncthreads();
    }

    // P6: wave0 = top-25 shuffle argmax; waves 1-3 = broadcast vmean to ALL ctx rows
    if (w == 0) {
        float v0 = Mv[lane], v1 = Mv[lane + 64];
        for (int it = 0; it < U; it++) {
            float bv; int bi;
            if (v1 > v0) { bv = v1; bi = lane + 64; } else { bv = v0; bi = lane; }
            #pragma unroll
            for (int o = 32; o > 0; o >>= 1) {
                float ov = __shfl_xor(bv, o);
                int   oi = __shfl_xor(bi, o);
                if (ov > bv || (ov == bv && oi < bi)) { bv = ov; bi = oi; }
            }
            if (lane == 0) topl[it] = bi;
            if (bi == lane) v0 = -1e30f;
            if (bi == lane + 64) v1 = -1e30f;
        }
    } else {
        for (int e = tid - 64; e < 128 * 16; e += 192) {
            int n = e >> 4, c4 = e & 15;
            short4 o;
            o.x = f2bf(vmean[c4 * 4 + 0]); o.y = f2bf(vmean[c4 * 4 + 1]);
            o.z = f2bf(vmean[c4 * 4 + 2]); o.w = f2bf(vmean[c4 * 4 + 3]);
            *(short4*)(cbase + (size_t)n * DM + c4 * 4) = o;
        }
    }
    __syncthreads();

    // P7: recompute scores for the 25 top rows into Stop
    {
        int rt = w & 1, cth = w >> 1;
        int u = rt * 16 + (lane & 15);
        int qrow = topl[u < U ? u : U - 1];
        const short* qp = base + (size_t)qrow * 1536;
        short8 a0 = *(const short8*)(qp + (lane >> 4) * 8);
        short8 a1 = *(const short8*)(qp + 32 + (lane >> 4) * 8);
        #pragma unroll
        for (int cti = 0; cti < 4; cti++) {
            int ct = cth * 4 + cti;
            int br = ct * 16 + (lane & 15);
            int cb0 = (lane >> 4) * 16;
            short8 b0 = *(const short8*)((char*)Kls + br * 128 + (cb0 ^ ((br & 7) << 4)));
            short8 b1 = *(const short8*)((char*)Kls + br * 128 + ((cb0 + 64) ^ ((br & 7) << 4)));
            f32x4 acc = {};
            acc = __builtin_amdgcn_mfma_f32_16x16x32_bf16(a0, b0, acc, 0, 0, 0);
            acc = __builtin_amdgcn_mfma_f32_16x16x32_bf16(a1, b1, acc, 0, 0, 0);
            int r0 = rt * 16 + ((lane >> 4) << 2);
            int c = ct * 16 + (lane & 15);
            #pragma unroll
            for (int j = 0; j < 4; j++) Stop[(r0 + j) * 130 + c] = acc[j] * 0.125f;
        }
    }
    __syncthreads();

    // P8: softmax of top rows -> Pb (bf16, swizzled); zero pad rows 25..31
    for (int e = tid; e < 7 * 128; e += 256)
        Pb[(25 + (e >> 7)) * 128 + (e & 127)] = 0;
    for (int it = w; it < U; it += 4) {
        float s0 = Stop[it * 130 + lane], s1 = Stop[it * 130 + 64 + lane];
        float mx = fmaxf(s0, s1);
        #pragma unroll
        for (int o = 32; o > 0; o >>= 1) mx = fmaxf(mx, __shfl_xor(mx, o));
        float e0 = expf(s0 - mx), e1 = expf(s1 - mx);
        float sum = e0 + e1;
        #pragma unroll
        for (int o = 32; o > 0; o >>= 1) sum += __shfl_xor(sum, o);
        float inv = 1.0f / sum;
        int sw = (it & 7) << 4;
        *(short*)((char*)Pb + it * 256 + ((2 * lane) ^ sw))        = f2bf(e0 * inv);
        *(short*)((char*)Pb + it * 256 + ((2 * (64 + lane)) ^ sw)) = f2bf(e1 * inv);
    }
    __syncthreads();

    // P9: PV via MFMA, scatter to top rows
    #pragma unroll
    for (int t = w * 2; t < w * 2 + 2; t++) {
        int rt = t >> 2, ct = t & 3;
        int pr = rt * 16 + (lane & 15);
        int vr = ct * 16 + (lane & 15);
        f32x4 acc = {};
        #pragma unroll
        for (int ks = 0; ks < 4; ks++) {
            int off = ks * 64 + (lane >> 4) * 16;
            short8 a = *(const short8*)((char*)Pb + pr * 256 + (off ^ ((pr & 7) << 4)));
            short8 b = *(const short8*)((char*)Vt + vr * 256 + (off ^ ((vr & 7) << 4)));
            acc = __builtin_amdgcn_mfma_f32_16x16x32_bf16(a, b, acc, 0, 0, 0);
        }
        int u0 = rt * 16 + ((lane >> 4) << 2), d = ct * 16 + (lane & 15);
        #pragma unroll
        for (int j = 0; j < 4; j++) {
            int u = u0 + j;
            if (u < U) cbase[(size_t)topl[u] * DM + d] = f2bf(acc[j]);
        }
    }
}

// ---------------- wave-parallel LayerNorm: 4 rows/block, bf16 in/out, no barriers ----------------
__global__ __launch_bounds__(256) void ln4(const short* __restrict__ a,
                                           const float* __restrict__ g,
                                           const float* __restrict__ beta,
                                           short* __restrict__ outb) {
    int w = threadIdx.x >> 6, lane = threadIdx.x & 63;
    size_t row = (size_t)blockIdx.x * 4 + w;
    short8 v = *(const short8*)(a + row * DM + lane * 8);
    float x[8];
    float s = 0.f, ss = 0.f;
    #pragma unroll
    for (int j = 0; j < 8; j++) { x[j] = bf2f(v[j]); s += x[j]; ss += x[j] * x[j]; }
    #pragma unroll
    for (int o = 32; o > 0; o >>= 1) { s += __shfl_xor(s, o); ss += __shfl_xor(ss, o); }
    float m = s * (1.0f / DM);
    float var = ss * (1.0f / DM) - m * m;
    float r = rsqrtf(var + 1e-5f);
    float4 g0 = *(const float4*)(g + lane * 8);
    float4 g1 = *(const float4*)(g + lane * 8 + 4);
    float4 b0 = *(const float4*)(beta + lane * 8);
    float4 b1 = *(const float4*)(beta + lane * 8 + 4);
    float gv[8] = {g0.x, g0.y, g0.z, g0.w, g1.x, g1.y, g1.z, g1.w};
    float bv[8] = {b0.x, b0.y, b0.z, b0.w, b1.x, b1.y, b1.z, b1.w};
    short8 o8;
    #pragma unroll
    for (int j = 0; j < 8; j++) o8[j] = f2bf((x[j] - m) * r * gv[j] + bv[j]);
    *(short8*)(outb + row * DM + lane * 8) = o8;
}

// ---------------- final LN + transpose: tokb(bc,p,d) -> featb(bc,d,p) ----------------
__global__ __launch_bounds__(256) void ln_transpose(const short* __restrict__ tokb,
                                                    const float* __restrict__ g,
                                                    const float* __restrict__ beta,
                                                    short* __restrict__ featb) {
    __shared__ short t[32][520];
    int pt = blockIdx.x, bc = blockIdx.y;      // pt: 0..3 (32-row tiles)
    int w = threadIdx.x >> 6, lane = threadIdx.x & 63;
    float4 g0 = *(const float4*)(g + lane * 8);
    float4 g1 = *(const float4*)(g + lane * 8 + 4);
    float4 be0 = *(const float4*)(beta + lane * 8);
    float4 be1 = *(const float4*)(beta + lane * 8 + 4);
    float gv[8] = {g0.x, g0.y, g0.z, g0.w, g1.x, g1.y, g1.z, g1.w};
    float bv[8] = {be0.x, be0.y, be0.z, be0.w, be1.x, be1.y, be1.z, be1.w};
    #pragma unroll
    for (int i = 0; i < 8; i++) {
        int pr = w * 8 + i;
        size_t row = (size_t)bc * NP + pt * 32 + pr;
        short8 v = *(const short8*)(tokb + row * DM + lane * 8);
        float x[8];
        float s = 0.f, ss = 0.f;
        #pragma unroll
        for (int j = 0; j < 8; j++) { x[j] = bf2f(v[j]); s += x[j]; ss += x[j] * x[j]; }
        #pragma unroll
        for (int o = 32; o > 0; o >>= 1) { s += __shfl_xor(s, o); ss += __shfl_xor(ss, o); }
        float m = s * (1.0f / DM);
        float var = ss * (1.0f / DM) - m * m;
        float r = rsqrtf(var + 1e-5f);
        short8 o8;
        #pragma unroll
        for (int j = 0; j < 8; j++) o8[j] = f2bf((x[j] - m) * r * gv[j] + bv[j]);
        *(short8*)(&t[pr][lane * 8]) = o8;
    }
    __syncthreads();
    // transposed write: each thread handles 2 d-columns, 32 p-values each (64 B rows)
    #pragma unroll
    for (int dd = 0; dd < 2; dd++) {
        int d = threadIdx.x * 2 + dd;
        uint32_t pk[16];
        #pragma unroll
        for (int p2 = 0; p2 < 16; p2++) {
            uint32_t lo = (uint16_t)t[2 * p2][d];
            uint32_t hi = (uint16_t)t[2 * p2 + 1][d];
            pk[p2] = lo | (hi << 16);
        }
        uint32_t* dst = (uint32_t*)(featb + (size_t)bc * (DM * NP) + (size_t)d * NP + pt * 32);
        #pragma unroll
        for (int q = 0; q < 4; q++) {
            int4 val; val.x = pk[q*4]; val.y = pk[q*4+1]; val.z = pk[q*4+2]; val.w = pk[q*4+3];
            *(int4*)(dst + q * 4) = val;
        }
    }
}

// ---------------- head MFMA split-K: partial[blk][96][64] ----------------
__global__ __launch_bounds__(256) void head_mfma(const float* __restrict__ hw,
                                                 const short* __restrict__ featb,
                                                 float* __restrict__ partial) {
    __shared__ short Als[96 * 64];
    __shared__ short Bls[64 * 64];
    int tid = threadIdx.x;
    int w = tid >> 6, lane = tid & 63;
    int wm = w >> 1, wn = w & 1;
    int kb = blockIdx.x * HKB;
    f32x4 acc[3][2] = {};
    const char* Ab = (const char*)Als;
    const char* Bb = (const char*)Bls;

    for (int kt = 0; kt < HKB; kt += 64) {
        #pragma unroll
        for (int i = 0; i < 6; i++) {
            int s = tid + i * 256;
            int row = s >> 4, c4 = s & 15;
            float4 v = *(const float4*)(hw + (size_t)row * 65536 + kb + kt + c4 * 4);
            short4 o; o.x = f2bf(v.x); o.y = f2bf(v.y); o.z = f2bf(v.z); o.w = f2bf(v.w);
            int boff = row * 128 + ((c4 * 8) ^ ((row & 7) << 4));
            *(short4*)((char*)Als + boff) = o;
        }
        #pragma unroll
        for (int i = 0; i < 4; i++) {
            int s = tid + i * 256;
            int row = s >> 4, c4 = s & 15;
            short4 o;
            if (row < BC) o = *(const short4*)(featb + (size_t)row * 65536 + kb + kt + c4 * 4);
            else { o.x = 0; o.y = 0; o.z = 0; o.w = 0; }
            int boff = row * 128 + ((c4 * 8) ^ ((row & 7) << 4));
            *(short4*)((char*)Bls + boff) = o;
        }
        __syncthreads();
        #pragma unroll
        for (int ks = 0; ks < 2; ks++) {
            int cb = ks * 64 + ((lane >> 4) << 4);
            short8 af[3], bfr[2];
            #pragma unroll
            for (int m = 0; m < 3; m++) {
                int r = wm * 48 + m * 16 + (lane & 15);
                af[m] = *(const short8*)(Ab + r * 128 + (cb ^ ((r & 7) << 4)));
            }
            #pragma unroll
            for (int n = 0; n < 2; n++) {
                int r = wn * 32 + n * 16 + (lane & 15);
                bfr[n] = *(const short8*)(Bb + r * 128 + (cb ^ ((r & 7) << 4)));
            }
            #pragma unroll
            for (int m = 0; m < 3; m++)
                #pragma unroll
                for (int n = 0; n < 2; n++)
                    acc[m][n] = __builtin_amdgcn_mfma_f32_16x16x32_bf16(af[m], bfr[n], acc[m][n], 0, 0, 0);
        }
        __syncthreads();
    }

    float* pb = partial + (size_t)blockIdx.x * (96 * 64);
    #pragma unroll
    for (int m = 0; m < 3; m++) {
        int rbase = wm * 48 + m * 16 + ((lane >> 4) << 2);
        #pragma unroll
        for (int n = 0; n < 2; n++) {
            int col = wn * 32 + n * 16 + (lane & 15);
            #pragma unroll
            for (int j = 0; j < 4; j++)
                pb[(rbase + j) * 64 + col] = acc[m][n][j];
        }
    }
}

// ---------------- finalize: full split-K reduction + bias + de-norm (one kernel) ----------------
__global__ void finalize(const float* __restrict__ partial, const float* __restrict__ hb,
                         const float* __restrict__ mean, const float* __restrict__ stdv,
                         float* __restrict__ out) {
    int i = blockIdx.x * 256 + threadIdx.x;
    if (i >= NB * 96 * CIN) return;
    int b = i / (96 * CIN);
    int r = i % (96 * CIN);
    int t = r / CIN, c = r % CIN;
    int bc = b * CIN + c;
    int j = t * 64 + bc;
    float s = 0.f;
    for (int blk = 0; blk < HNB; blk++) s += partial[(size_t)blk * 6144 + j];
    out[i] = (s + hb[t]) * stdv[bc] + mean[bc];
}

// ---------------- launch ----------------
extern "C" void kernel_launch(void* const* d_in, const int* in_sizes, int n_in,
                              void* d_out, int out_size, void* d_ws, size_t ws_size,
                              hipStream_t stream) {
    (void)in_sizes; (void)n_in; (void)out_size; (void)ws_size;
    const float* x_enc   = (const float*)d_in[0];
    const float* patch_W = (const float*)d_in[4];
    const float* Wq  = (const float*)d_in[5];
    const float* bq  = (const float*)d_in[6];
    const float* Wk  = (const float*)d_in[7];
    const float* bk  = (const float*)d_in[8];
    const float* Wv  = (const float*)d_in[9];
    const float* bv  = (const float*)d_in[10];
    const float* Wo  = (const float*)d_in[11];
    const float* bo  = (const float*)d_in[12];
    const float* c1W = (const float*)d_in[13];
    const float* c1b = (const float*)d_in[14];
    const float* c2W = (const float*)d_in[15];
    const float* c2b = (const float*)d_in[16];
    const float* ln1g = (const float*)d_in[17];
    const float* ln1b = (const float*)d_in[18];
    const float* ln2g = (const float*)d_in[19];
    const float* ln2b = (const float*)d_in[20];
    const float* encg = (const float*)d_in[21];
    const float* encb = (const float*)d_in[22];
    const float* headW = (const float*)d_in[23];
    const float* headb = (const float*)d_in[24];
    float* out = (float*)d_out;

    float* ws = (float*)d_ws;
    float* mean = ws + 0;
    float* stdv = ws + 64;
    float* bqkv = ws + 128;                 // 2*1536 floats
    int*   samp = (int*)(ws + 6144);        // 6400 ints
    size_t off = 32768;
    const size_t T = (size_t)NTOK * DM;     // 3,670,016
    float* partial = ws + off; off += T;      // head split-K partials (256*6144)
    // bf16 region
    short* sbase = (short*)(ws + off);
    size_t soff = 0;
    short* tok_b  = sbase + soff; soff += T;
    short* ctx_b  = sbase + soff; soff += T;
    short* x1_b   = sbase + soff; soff += T;
    short* pA_b   = sbase + soff; soff += T;
    short* qkv_b  = sbase + soff; soff += 3 * T;            // bf16 QKV
    short* ffn_b  = sbase + soff; soff += (size_t)NTOK * DFF;
    short* featb  = ffn_b;                  // reuse: ffn_b dead after encoder loop
    short* wqkv_b = sbase + soff; soff += 2 * 1536 * DM;
    short* wo_b   = sbase + soff; soff += 2 * DM * DM;
    short* c1w_b  = sbase + soff; soff += 2 * (size_t)DFF * DM;
    short* c2w_b  = sbase + soff; soff += 2 * (size_t)DM * DFF;

    prep_weights<<<6202, 256, 0, stream>>>(Wq, Wk, Wv, bq, bk, bv, Wo, c1W, c2W, x_enc,
                                           wqkv_b, bqkv, wo_b, c1w_b, c2w_b, samp, mean, stdv);
    patch_embed<<<dim3(NP, BC), 128, 0, stream>>>(x_enc, patch_W, mean, stdv, tok_b);

    for (int l = 0; l < 2; l++) {
        // QKV (bf16 out)
        gemm_mfma<0><<<dim3(56, 12), 256, 0, stream>>>(tok_b, wqkv_b + (size_t)l * 1536 * DM, bqkv + l * 1536, qkv_b, NTOK, 1536, DM);
        attn_fused<<<448, 256, 0, stream>>>(qkv_b, samp + l * 3200, ctx_b);
        // Wo + residual(tok_b) folded -> pA_b; then LN1 -> x1_b
        gemm_mfma64<<<dim3(112, 4), 256, 0, stream>>>(ctx_b, wo_b + (size_t)l * DM * DM, bo + l * DM, tok_b, pA_b, NTOK, DM, DM);
        ln4<<<NTOK / 4, 256, 0, stream>>>(pA_b, ln1g + l * DM, ln1b + l * DM, x1_b);
        gemm_mfma<1><<<dim3(56, 16), 256, 0, stream>>>(x1_b, c1w_b + (size_t)l * DFF * DM, c1b + l * DFF, ffn_b, NTOK, DFF, DM);
        // FFN2 + residual(x1_b) folded -> pA_b; then LN2 -> tok_b
        gemm_mfma64<<<dim3(112, 4), 256, 0, stream>>>(ffn_b, c2w_b + (size_t)l * DM * DFF, c2b + l * DM, x1_b, pA_b, NTOK, DM, DFF);
        ln4<<<NTOK / 4, 256, 0, stream>>>(pA_b, ln2g + l * DM, ln2b + l * DM, tok_b);
    }

    // final encoder LN fused with transpose -> featb
    ln_transpose<<<dim3(4, BC), 256, 0, stream>>>(tok_b, encg, encb, featb);
    head_mfma<<<HNB, 256, 0, stream>>>(headW, featb, partial);
    finalize<<<21, 256, 0, stream>>>(partial, headb, mean, stdv, out);
}

// Round 13
// 299.552 us; speedup vs baseline: 1.4133x; 1.0036x over previous
//
#include <hip/hip_runtime.h>
#include <math.h>
#include <stdint.h>

#define SEQ   1024
#define CIN   7
#define NB    8
#define BC    56          // NB*CIN
#define NP    128         // patches
#define DM    512
#define NH    8
#define DH    64
#define DFF   2048
#define U     25
#define NTOK  (BC*NP)     // 7168
#define PE_COEF (-9.210340371976184f / 512.0f)  // -ln(10000)/DM
#define HKB   256         // head: K elems per split-K block
#define HNB   256         // head: number of split-K blocks (HKB*HNB = 65536)

typedef __attribute__((ext_vector_type(8))) short short8;
typedef __attribute__((ext_vector_type(4))) float f32x4;

__device__ __forceinline__ short f2bf(float x) {
    union { float f; uint32_t u; } v; v.f = x;
    uint32_t r = v.u + 0x7FFFu + ((v.u >> 16) & 1u);
    return (short)(r >> 16);
}
__device__ __forceinline__ float bf2f(short x) {
    union { uint32_t u; float f; } v; v.u = ((uint32_t)(uint16_t)x) << 16;
    return v.f;
}

__device__ __forceinline__ void gl_lds16(const void* g, void* s) {
    __builtin_amdgcn_global_load_lds((const __attribute__((address_space(1))) void*)g,
                                     (__attribute__((address_space(3))) void*)s, 16, 0, 0);
}

// ---------------- threefry2x32-20 (JAX PRNG) ----------------
__device__ __forceinline__ void tf_round(uint32_t& x0, uint32_t& x1, uint32_t r) {
    x0 += x1; x1 = (x1 << r) | (x1 >> (32u - r)); x1 ^= x0;
}
__device__ void threefry2x32(uint32_t k0, uint32_t k1, uint32_t x0, uint32_t x1,
                             uint32_t& o0, uint32_t& o1) {
    uint32_t ks[3] = { k0, k1, k0 ^ k1 ^ 0x1BD11BDAu };
    x0 += ks[0]; x1 += ks[1];
    const uint32_t rotA[4] = {13u, 15u, 26u, 6u}, rotB[4] = {17u, 29u, 16u, 24u};
    #pragma unroll
    for (int i = 0; i < 5; i++) {
        const uint32_t* rr = (i & 1) ? rotB : rotA;
        tf_round(x0, x1, rr[0]); tf_round(x0, x1, rr[1]);
        tf_round(x0, x1, rr[2]); tf_round(x0, x1, rr[3]);
        x0 += ks[(i + 1) % 3];
        x1 += ks[(i + 2) % 3] + (uint32_t)(i + 1);
    }
    o0 = x0; o1 = x1;
}

// ---------------- fused prep: pack QKV weights, convert Wo/c1W/c2W, samp, stats ----------------
__global__ void prep_weights(const float* __restrict__ Wq, const float* __restrict__ Wk,
                             const float* __restrict__ Wv, const float* __restrict__ bq,
                             const float* __restrict__ bk, const float* __restrict__ bv,
                             const float* __restrict__ Wo, const float* __restrict__ c1W,
                             const float* __restrict__ c2W, const float* __restrict__ x_enc,
                             short* __restrict__ wqkv, float* __restrict__ bqkv,
                             short* __restrict__ wo_b, short* __restrict__ c1w_b,
                             short* __restrict__ c2w_b, int* __restrict__ samp,
                             float* __restrict__ mean, float* __restrict__ stdv) {
    int blk = blockIdx.x, tid = threadIdx.x;
    if (blk < 1536) {                       // pack_qkv: 2*1536*128 float4 slots
        int idx = blk * 256 + tid;
        int k4 = idx & 127;
        int n  = (idx >> 7) % 1536;
        int l  = idx / (1536 * 128);
        int sel3 = n >> 9;
        int nn = n & 511;
        const float* src = sel3 == 0 ? Wq : sel3 == 1 ? Wk : Wv;
        float4 v = *(const float4*)(src + ((size_t)l * DM + nn) * DM + k4 * 4);
        short4 o; o.x = f2bf(v.x); o.y = f2bf(v.y); o.z = f2bf(v.z); o.w = f2bf(v.w);
        *(short4*)(wqkv + ((size_t)l * 1536 + n) * DM + k4 * 4) = o;
        if (k4 == 0) {
            const float* bsrc = sel3 == 0 ? bq : sel3 == 1 ? bk : bv;
            bqkv[l * 1536 + n] = bsrc[l * DM + nn];
        }
    } else if (blk < 6144) {                // converts
        const float* in; short* out; int i;
        if (blk < 2048)      { in = Wo;  out = wo_b;  i = (blk - 1536) * 256 + tid; }
        else if (blk < 4096) { in = c1W; out = c1w_b; i = (blk - 2048) * 256 + tid; }
        else                 { in = c2W; out = c2w_b; i = (blk - 4096) * 256 + tid; }
        float4 v = ((const float4*)in)[i];
        short4 o; o.x = f2bf(v.x); o.y = f2bf(v.y); o.z = f2bf(v.z); o.w = f2bf(v.w);
        ((short4*)out)[i] = o;
    } else if (blk < 6146) {                // samp: 2 blocks
        int l = blk - 6144;
        uint32_t s0, s1; threefry2x32(0u, 42u, 0u, (uint32_t)l, s0, s1);
        uint32_t a0, a1, b0, b1;
        threefry2x32(s0, s1, 0u, 2u, a0, a1);
        threefry2x32(s0, s1, 1u, 3u, b0, b1);
        uint32_t k20 = a1, k21 = b1;
        for (int i = tid; i < 1600; i += 256) {
            uint32_t o0, o1;
            threefry2x32(k20, k21, (uint32_t)i, (uint32_t)(1600 + i), o0, o1);
            samp[l * 3200 + i]        = (int)(o0 & 127u);
            samp[l * 3200 + 1600 + i] = (int)(o1 & 127u);
        }
    } else {                                 // stats: 56 blocks, one per (b,c)
        int bc = blk - 6146;
        int b = bc / CIN, c = bc % CIN;
        const float* base = x_enc + (size_t)b * SEQ * CIN + c;
        float s = 0.f, ss = 0.f;
        for (int i = tid; i < SEQ; i += 256) {
            float v = base[(size_t)i * CIN];
            s += v; ss += v * v;
        }
        __shared__ float rs[256], rss[256];
        rs[tid] = s; rss[tid] = ss; __syncthreads();
        for (int o = 128; o > 0; o >>= 1) {
            if (tid < o) { rs[tid] += rs[tid + o]; rss[tid] += rss[tid + o]; }
            __syncthreads();
        }
        if (tid == 0) {
            float m = rs[0] / SEQ;
            float v = rss[0] / SEQ - m * m;
            mean[bc] = m;
            stdv[bc] = sqrtf(v + 1e-5f);
        }
    }
}

// ---------------- patch embedding + sinusoidal PE (bf16 out) ----------------
__global__ void patch_embed(const float* __restrict__ x, const float* __restrict__ pw,
                            const float* __restrict__ mean, const float* __restrict__ stdv,
                            short* __restrict__ tokb) {
    int p = blockIdx.x, bc = blockIdx.y;
    int b = bc / CIN, c = bc % CIN;
    __shared__ float xs[16];
    if (threadIdx.x < 16) {
        int i = p * 8 + threadIdx.x;
        if (i > SEQ - 1) i = SEQ - 1;   // edge pad
        xs[threadIdx.x] = (x[(size_t)b * SEQ * CIN + (size_t)i * CIN + c] - mean[bc]) / stdv[bc];
    }
    __syncthreads();
    for (int d = threadIdx.x; d < DM; d += blockDim.x) {
        float acc = 0.f;
        const float* wr = pw + d * 16;
        #pragma unroll
        for (int t = 0; t < 16; t++) acc += xs[t] * wr[t];
        int k2 = d & ~1;
        float ang = (float)p * __expf((float)k2 * PE_COEF);
        acc += (d & 1) ? __cosf(ang) : __sinf(ang);
        tokb[((size_t)bc * NP + p) * DM + d] = f2bf(acc);
    }
}

// ---------------- MFMA GEMM 128x128, 2-phase double-buffered pipeline ----------------
template<int ACT>   // ACT: 0 none, 1 fast GELU; bf16 out
__global__ __launch_bounds__(256) void gemm_mfma(const short* __restrict__ A,
                                                 const short* __restrict__ W,
                                                 const float* __restrict__ bias,
                                                 short* __restrict__ Cb,
                                                 int M, int N, int K) {
    __shared__ short LDSU[2][16384];   // [buf][ A:0..8191 | B:8192..16383 ]  64 KB
    int tid = threadIdx.x;
    int w = tid >> 6, lane = tid & 63;
    int row0 = blockIdx.x * 128, col0 = blockIdx.y * 128;
    int wrow = (w >> 1) * 64, wcol = (w & 1) * 64;
    int nt = K >> 6;
    f32x4 acc[4][4] = {};

    auto stage = [&](int b, int kt) {
        #pragma unroll
        for (int i = 0; i < 4; i++) {
            int L = i * 4096 + w * 1024 + lane * 16;    // linear LDS byte offset
            int row = L >> 7;
            int cb  = L & 127;
            int scb = cb ^ ((row & 7) << 4);             // inverse-swizzled source col
            gl_lds16(A + (size_t)(row0 + row) * K + kt + (scb >> 1),
                     (char*)&LDSU[b][0] + i * 4096 + w * 1024);
            gl_lds16(W + (size_t)(col0 + row) * K + kt + (scb >> 1),
                     (char*)&LDSU[b][8192] + i * 4096 + w * 1024);
        }
    };

    stage(0, 0);
    __syncthreads();
    int cur = 0;
    for (int t = 0; t < nt; t++) {
        if (t + 1 < nt) stage(cur ^ 1, (t + 1) * 64);   // prefetch under compute
        const char* Ab = (const char*)&LDSU[cur][0];
        const char* Bb = (const char*)&LDSU[cur][8192];
        #pragma unroll
        for (int ks = 0; ks < 2; ks++) {
            int cb = ks * 64 + ((lane >> 4) << 4);
            short8 af[4], bfr[4];
            #pragma unroll
            for (int m = 0; m < 4; m++) {
                int r = wrow + m * 16 + (lane & 15);
                af[m] = *(const short8*)(Ab + r * 128 + (cb ^ ((r & 7) << 4)));
            }
            #pragma unroll
            for (int n = 0; n < 4; n++) {
                int r = wcol + n * 16 + (lane & 15);
                bfr[n] = *(const short8*)(Bb + r * 128 + (cb ^ ((r & 7) << 4)));
            }
            #pragma unroll
            for (int m = 0; m < 4; m++)
                #pragma unroll
                for (int n = 0; n < 4; n++)
                    acc[m][n] = __builtin_amdgcn_mfma_f32_16x16x32_bf16(af[m], bfr[n], acc[m][n], 0, 0, 0);
        }
        __syncthreads();
        cur ^= 1;
    }

    #pragma unroll
    for (int m = 0; m < 4; m++) {
        int rbase = row0 + wrow + m * 16 + ((lane >> 4) << 2);
        #pragma unroll
        for (int n = 0; n < 4; n++) {
            int col = col0 + wcol + n * 16 + (lane & 15);
            float bval = bias[col];
            #pragma unroll
            for (int j = 0; j < 4; j++) {
                float v = acc[m][n][j] + bval;
                if (ACT == 1) {
                    float u = 0.7978845608f * (v + 0.044715f * v * v * v);
                    float e = exp2f(2.8853900817779268f * u);
                    v = v - v / (e + 1.0f);
                }
                Cb[(size_t)(rbase + j) * N + col] = f2bf(v);
            }
        }
    }
}

// ---------------- MFMA GEMM 64x128 tile (+ optional bf16 residual), bf16 out ----------------
template<int HASRES>
__global__ __launch_bounds__(256) void gemm_mfma64(const short* __restrict__ A,
                                                   const short* __restrict__ W,
                                                   const float* __restrict__ bias,
                                                   const short* __restrict__ residb,
                                                   short* __restrict__ Cb,
                                                   int M, int N, int K) {
    __shared__ short LDSU[2][12288];   // [buf][ A:0..4095 sh | B:4096..12287 sh ] 48 KB
    int tid = threadIdx.x;
    int w = tid >> 6, lane = tid & 63;
    int row0 = blockIdx.x * 64, col0 = blockIdx.y * 128;
    int nt = K >> 6;
    f32x4 acc[4][2] = {};

    auto stage = [&](int b, int kt) {
        #pragma unroll
        for (int i = 0; i < 2; i++) {
            int L = (i * 4 + w) * 1024 + lane * 16;
            int row = L >> 7, cb = L & 127;
            int scb = cb ^ ((row & 7) << 4);
            gl_lds16(A + (size_t)(row0 + row) * K + kt + (scb >> 1),
                     (char*)&LDSU[b][0] + (i * 4 + w) * 1024);
        }
        #pragma unroll
        for (int i = 0; i < 4; i++) {
            int L = (i * 4 + w) * 1024 + lane * 16;
            int row = L >> 7, cb = L & 127;
            int scb = cb ^ ((row & 7) << 4);
            gl_lds16(W + (size_t)(col0 + row) * K + kt + (scb >> 1),
                     (char*)&LDSU[b][4096] + (i * 4 + w) * 1024);
        }
    };

    stage(0, 0);
    __syncthreads();
    int cur = 0;
    for (int t = 0; t < nt; t++) {
        if (t + 1 < nt) stage(cur ^ 1, (t + 1) * 64);
        const char* Ab = (const char*)&LDSU[cur][0];
        const char* Bb = (const char*)&LDSU[cur][4096];
        #pragma unroll
        for (int ks = 0; ks < 2; ks++) {
            int cb = ks * 64 + ((lane >> 4) << 4);
            short8 af[4], bfr[2];
            #pragma unroll
            for (int m = 0; m < 4; m++) {
                int r = m * 16 + (lane & 15);
                af[m] = *(const short8*)(Ab + r * 128 + (cb ^ ((r & 7) << 4)));
            }
            #pragma unroll
            for (int n = 0; n < 2; n++) {
                int r = w * 32 + n * 16 + (lane & 15);
                bfr[n] = *(const short8*)(Bb + r * 128 + (cb ^ ((r & 7) << 4)));
            }
            #pragma unroll
            for (int m = 0; m < 4; m++)
                #pragma unroll
                for (int n = 0; n < 2; n++)
                    acc[m][n] = __builtin_amdgcn_mfma_f32_16x16x32_bf16(af[m], bfr[n], acc[m][n], 0, 0, 0);
        }
        __syncthreads();
        cur ^= 1;
    }

    #pragma unroll
    for (int m = 0; m < 4; m++) {
        int rbase = row0 + m * 16 + ((lane >> 4) << 2);
        #pragma unroll
        for (int n = 0; n < 2; n++) {
            int col = col0 + w * 32 + n * 16 + (lane & 15);
            float bval = bias[col];
            #pragma unroll
            for (int j = 0; j < 4; j++) {
                float v = acc[m][n][j] + bval;
                if (HASRES) v += bf2f(residb[(size_t)(rbase + j) * N + col]);
                Cb[(size_t)(rbase + j) * N + col] = f2bf(v);
            }
        }
    }
}

// ---------------- fused ProbSparse attention (one block per (bc,h)) ----------------
__global__ __launch_bounds__(256, 2) void attn_fused(const short* __restrict__ qkvb,
                                                     const int* __restrict__ samp,
                                                     short* __restrict__ ctxb) {
    __shared__ float Sbuf[64 * 130];   // 33.28 KB; overlays Stop[32*130] + Pb
    __shared__ short Vt[64 * 128];     // 16 KB, XOR-swizzled rows of 256 B
    __shared__ short Kls[128 * 64];    // 16 KB, XOR-swizzled rows of 128 B
    __shared__ float Mv[128];
    __shared__ int   topl[32];
    __shared__ float vmean[64];
    __shared__ float vpart[256];

    float* Stop = Sbuf;                          // 32 x 130 fp32
    short* Pb   = (short*)(Sbuf + 32 * 130);     // 32 x 128 bf16, XOR-swizzled

    int bh = blockIdx.x, bc = bh >> 3, h = bh & 7;
    int tid = threadIdx.x, w = tid >> 6, lane = tid & 63;
    const short* base = qkvb + (size_t)bc * NP * 1536 + h * DH;
    short* cbase = ctxb + (size_t)bc * NP * DM + h * DH;

    // P0: stage K (swizzled rows) + V transposed (swizzled)
    for (int e = tid; e < 1024; e += 256) {
        int row = e >> 3, c8 = e & 7;
        short8 kv = *(const short8*)(base + (size_t)row * 1536 + 512 + c8 * 8);
        *(short8*)((char*)Kls + row * 128 + ((c8 * 16) ^ ((row & 7) << 4))) = kv;
        short8 vv = *(const short8*)(base + (size_t)row * 1536 + 1024 + c8 * 8);
        #pragma unroll
        for (int j = 0; j < 8; j++) {
            int d = c8 * 8 + j;
            *(short*)((char*)Vt + d * 256 + ((2 * row) ^ ((d & 7) << 4))) = vv[j];
        }
    }
    __syncthreads();
    {
        int d = tid & 63, part = tid >> 6;
        float s = 0.f;
        #pragma unroll
        for (int i4 = 0; i4 < 4; i4++) {
            short8 v = *(const short8*)((char*)Vt + d * 256 + ((part * 64 + i4 * 16) ^ ((d & 7) << 4)));
            #pragma unroll
            for (int j = 0; j < 8; j++) s += bf2f(v[j]);
        }
        vpart[part * 64 + d] = s;
    }

    // P2: S halves (64 rows each) + M-score gather per half
    for (int half = 0; half < 2; half++) {
        int ar = half * 64 + 16 * w + (lane & 15);
        const short* qp = base + (size_t)ar * 1536;
        short8 a0 = *(const short8*)(qp + (lane >> 4) * 8);
        short8 a1 = *(const short8*)(qp + 32 + (lane >> 4) * 8);
        #pragma unroll 2
        for (int ct = 0; ct < 8; ct++) {
            int br = ct * 16 + (lane & 15);
            int cb0 = (lane >> 4) * 16;
            short8 b0 = *(const short8*)((char*)Kls + br * 128 + (cb0 ^ ((br & 7) << 4)));
            short8 b1 = *(const short8*)((char*)Kls + br * 128 + ((cb0 + 64) ^ ((br & 7) << 4)));
            f32x4 acc = {};
            acc = __builtin_amdgcn_mfma_f32_16x16x32_bf16(a0, b0, acc, 0, 0, 0);
            acc = __builtin_amdgcn_mfma_f32_16x16x32_bf16(a1, b1, acc, 0, 0, 0);
            int r0 = 16 * w + ((lane >> 4) << 2);
            int c = ct * 16 + (lane & 15);
            #pragma unroll
            for (int j = 0; j < 4; j++) Sbuf[(r0 + j) * 130 + c] = acc[j] * 0.125f;
        }
        __syncthreads();
        if (tid < 64) {
            int r = half * 64 + tid;
            const int* sp = samp + r * U;
            const float* Srow = &Sbuf[tid * 130];
            float mx = -1e30f, sm = 0.f;
            #pragma unroll
            for (int s = 0; s < U; s++) { float v = Srow[sp[s]]; mx = fmaxf(mx, v); sm += v; }
            Mv[r] = mx - sm * (1.0f / U);
        } else if (half == 0 && tid < 128) {
            int d = tid - 64;
            vmean[d] = (vpart[d] + vpart[64 + d] + vpart[128 + d] + vpart[192 + d]) * (1.0f / 128.0f);
        }
        __syncthreads();
    }

    // P6: wave0 = top-25 shuffle argmax; waves 1-3 = broadcast vmean to ALL ctx rows
    if (w == 0) {
        float v0 = Mv[lane], v1 = Mv[lane + 64];
        for (int it = 0; it < U; it++) {
            float bv; int bi;
            if (v1 > v0) { bv = v1; bi = lane + 64; } else { bv = v0; bi = lane; }
            #pragma unroll
            for (int o = 32; o > 0; o >>= 1) {
                float ov = __shfl_xor(bv, o);
                int   oi = __shfl_xor(bi, o);
                if (ov > bv || (ov == bv && oi < bi)) { bv = ov; bi = oi; }
            }
            if (lane == 0) topl[it] = bi;
            if (bi == lane) v0 = -1e30f;
            if (bi == lane + 64) v1 = -1e30f;
        }
    } else {
        for (int e = tid - 64; e < 128 * 16; e += 192) {
            int n = e >> 4, c4 = e & 15;
            short4 o;
            o.x = f2bf(vmean[c4 * 4 + 0]); o.y = f2bf(vmean[c4 * 4 + 1]);
            o.z = f2bf(vmean[c4 * 4 + 2]); o.w = f2bf(vmean[c4 * 4 + 3]);
            *(short4*)(cbase + (size_t)n * DM + c4 * 4) = o;
        }
    }
    __syncthreads();

    // P7: recompute scores for the 25 top rows into Stop
    {
        int rt = w & 1, cth = w >> 1;
        int u = rt * 16 + (lane & 15);
        int qrow = topl[u < U ? u : U - 1];
        const short* qp = base + (size_t)qrow * 1536;
        short8 a0 = *(const short8*)(qp + (lane >> 4) * 8);
        short8 a1 = *(const short8*)(qp + 32 + (lane >> 4) * 8);
        #pragma unroll
        for (int cti = 0; cti < 4; cti++) {
            int ct = cth * 4 + cti;
            int br = ct * 16 + (lane & 15);
            int cb0 = (lane >> 4) * 16;
            short8 b0 = *(const short8*)((char*)Kls + br * 128 + (cb0 ^ ((br & 7) << 4)));
            short8 b1 = *(const short8*)((char*)Kls + br * 128 + ((cb0 + 64) ^ ((br & 7) << 4)));
            f32x4 acc = {};
            acc = __builtin_amdgcn_mfma_f32_16x16x32_bf16(a0, b0, acc, 0, 0, 0);
            acc = __builtin_amdgcn_mfma_f32_16x16x32_bf16(a1, b1, acc, 0, 0, 0);
            int r0 = rt * 16 + ((lane >> 4) << 2);
            int c = ct * 16 + (lane & 15);
            #pragma unroll
            for (int j = 0; j < 4; j++) Stop[(r0 + j) * 130 + c] = acc[j] * 0.125f;
        }
    }
    __syncthreads();

    // P8: softmax of top rows -> Pb (bf16, swizzled); zero pad rows 25..31
    for (int e = tid; e < 7 * 128; e += 256)
        Pb[(25 + (e >> 7)) * 128 + (e & 127)] = 0;
    for (int it = w; it < U; it += 4) {
        float s0 = Stop[it * 130 + lane], s1 = Stop[it * 130 + 64 + lane];
        float mx = fmaxf(s0, s1);
        #pragma unroll
        for (int o = 32; o > 0; o >>= 1) mx = fmaxf(mx, __shfl_xor(mx, o));
        float e0 = expf(s0 - mx), e1 = expf(s1 - mx);
        float sum = e0 + e1;
        #pragma unroll
        for (int o = 32; o > 0; o >>= 1) sum += __shfl_xor(sum, o);
        float inv = 1.0f / sum;
        int sw = (it & 7) << 4;
        *(short*)((char*)Pb + it * 256 + ((2 * lane) ^ sw))        = f2bf(e0 * inv);
        *(short*)((char*)Pb + it * 256 + ((2 * (64 + lane)) ^ sw)) = f2bf(e1 * inv);
    }
    __syncthreads();

    // P9: PV via MFMA, scatter to top rows
    #pragma unroll
    for (int t = w * 2; t < w * 2 + 2; t++) {
        int rt = t >> 2, ct = t & 3;
        int pr = rt * 16 + (lane & 15);
        int vr = ct * 16 + (lane & 15);
        f32x4 acc = {};
        #pragma unroll
        for (int ks = 0; ks < 4; ks++) {
            int off = ks * 64 + (lane >> 4) * 16;
            short8 a = *(const short8*)((char*)Pb + pr * 256 + (off ^ ((pr & 7) << 4)));
            short8 b = *(const short8*)((char*)Vt + vr * 256 + (off ^ ((vr & 7) << 4)));
            acc = __builtin_amdgcn_mfma_f32_16x16x32_bf16(a, b, acc, 0, 0, 0);
        }
        int u0 = rt * 16 + ((lane >> 4) << 2), d = ct * 16 + (lane & 15);
        #pragma unroll
        for (int j = 0; j < 4; j++) {
            int u = u0 + j;
            if (u < U) cbase[(size_t)topl[u] * DM + d] = f2bf(acc[j]);
        }
    }
}

// ---------------- wave-parallel LayerNorm: 4 rows/block, bf16 in/out, no barriers ----------------
__global__ __launch_bounds__(256) void ln4(const short* __restrict__ a,
                                           const float* __restrict__ g,
                                           const float* __restrict__ beta,
                                           short* __restrict__ outb) {
    int w = threadIdx.x >> 6, lane = threadIdx.x & 63;
    size_t row = (size_t)blockIdx.x * 4 + w;
    short8 v = *(const short8*)(a + row * DM + lane * 8);
    float x[8];
    float s = 0.f, ss = 0.f;
    #pragma unroll
    for (int j = 0; j < 8; j++) { x[j] = bf2f(v[j]); s += x[j]; ss += x[j] * x[j]; }
    #pragma unroll
    for (int o = 32; o > 0; o >>= 1) { s += __shfl_xor(s, o); ss += __shfl_xor(ss, o); }
    float m = s * (1.0f / DM);
    float var = ss * (1.0f / DM) - m * m;
    float r = rsqrtf(var + 1e-5f);
    float4 g0 = *(const float4*)(g + lane * 8);
    float4 g1 = *(const float4*)(g + lane * 8 + 4);
    float4 b0 = *(const float4*)(beta + lane * 8);
    float4 b1 = *(const float4*)(beta + lane * 8 + 4);
    float gv[8] = {g0.x, g0.y, g0.z, g0.w, g1.x, g1.y, g1.z, g1.w};
    float bv[8] = {b0.x, b0.y, b0.z, b0.w, b1.x, b1.y, b1.z, b1.w};
    short8 o8;
    #pragma unroll
    for (int j = 0; j < 8; j++) o8[j] = f2bf((x[j] - m) * r * gv[j] + bv[j]);
    *(short8*)(outb + row * DM + lane * 8) = o8;
}

// ---------------- final LN + transpose: tokb(bc,p,d) -> featb(bc,d,p) ----------------
__global__ __launch_bounds__(256) void ln_transpose(const short* __restrict__ tokb,
                                                    const float* __restrict__ g,
                                                    const float* __restrict__ beta,
                                                    short* __restrict__ featb) {
    __shared__ short t[32][520];
    int pt = blockIdx.x, bc = blockIdx.y;      // pt: 0..3 (32-row tiles)
    int w = threadIdx.x >> 6, lane = threadIdx.x & 63;
    float4 g0 = *(const float4*)(g + lane * 8);
    float4 g1 = *(const float4*)(g + lane * 8 + 4);
    float4 be0 = *(const float4*)(beta + lane * 8);
    float4 be1 = *(const float4*)(beta + lane * 8 + 4);
    float gv[8] = {g0.x, g0.y, g0.z, g0.w, g1.x, g1.y, g1.z, g1.w};
    float bv[8] = {be0.x, be0.y, be0.z, be0.w, be1.x, be1.y, be1.z, be1.w};
    #pragma unroll
    for (int i = 0; i < 8; i++) {
        int pr = w * 8 + i;
        size_t row = (size_t)bc * NP + pt * 32 + pr;
        short8 v = *(const short8*)(tokb + row * DM + lane * 8);
        float x[8];
        float s = 0.f, ss = 0.f;
        #pragma unroll
        for (int j = 0; j < 8; j++) { x[j] = bf2f(v[j]); s += x[j]; ss += x[j] * x[j]; }
        #pragma unroll
        for (int o = 32; o > 0; o >>= 1) { s += __shfl_xor(s, o); ss += __shfl_xor(ss, o); }
        float m = s * (1.0f / DM);
        float var = ss * (1.0f / DM) - m * m;
        float r = rsqrtf(var + 1e-5f);
        short8 o8;
        #pragma unroll
        for (int j = 0; j < 8; j++) o8[j] = f2bf((x[j] - m) * r * gv[j] + bv[j]);
        *(short8*)(&t[pr][lane * 8]) = o8;
    }
    __syncthreads();
    // transposed write: each thread handles 2 d-columns, 32 p-values each (64 B rows)
    #pragma unroll
    for (int dd = 0; dd < 2; dd++) {
        int d = threadIdx.x * 2 + dd;
        uint32_t pk[16];
        #pragma unroll
        for (int p2 = 0; p2 < 16; p2++) {
            uint32_t lo = (uint16_t)t[2 * p2][d];
            uint32_t hi = (uint16_t)t[2 * p2 + 1][d];
            pk[p2] = lo | (hi << 16);
        }
        uint32_t* dst = (uint32_t*)(featb + (size_t)bc * (DM * NP) + (size_t)d * NP + pt * 32);
        #pragma unroll
        for (int q = 0; q < 4; q++) {
            int4 val; val.x = pk[q*4]; val.y = pk[q*4+1]; val.z = pk[q*4+2]; val.w = pk[q*4+3];
            *(int4*)(dst + q * 4) = val;
        }
    }
}

// ---------------- head MFMA split-K: partial[blk][96][64] ----------------
__global__ __launch_bounds__(256) void head_mfma(const float* __restrict__ hw,
                                                 const short* __restrict__ featb,
                                                 float* __restrict__ partial) {
    __shared__ short Als[96 * 64];
    __shared__ short Bls[64 * 64];
    int tid = threadIdx.x;
    int w = tid >> 6, lane = tid & 63;
    int wm = w >> 1, wn = w & 1;
    int kb = blockIdx.x * HKB;
    f32x4 acc[3][2] = {};
    const char* Ab = (const char*)Als;
    const char* Bb = (const char*)Bls;

    for (int kt = 0; kt < HKB; kt += 64) {
        #pragma unroll
        for (int i = 0; i < 6; i++) {
            int s = tid + i * 256;
            int row = s >> 4, c4 = s & 15;
            float4 v = *(const float4*)(hw + (size_t)row * 65536 + kb + kt + c4 * 4);
            short4 o; o.x = f2bf(v.x); o.y = f2bf(v.y); o.z = f2bf(v.z); o.w = f2bf(v.w);
            int boff = row * 128 + ((c4 * 8) ^ ((row & 7) << 4));
            *(short4*)((char*)Als + boff) = o;
        }
        #pragma unroll
        for (int i = 0; i < 4; i++) {
            int s = tid + i * 256;
            int row = s >> 4, c4 = s & 15;
            short4 o;
            if (row < BC) o = *(const short4*)(featb + (size_t)row * 65536 + kb + kt + c4 * 4);
            else { o.x = 0; o.y = 0; o.z = 0; o.w = 0; }
            int boff = row * 128 + ((c4 * 8) ^ ((row & 7) << 4));
            *(short4*)((char*)Bls + boff) = o;
        }
        __syncthreads();
        #pragma unroll
        for (int ks = 0; ks < 2; ks++) {
            int cb = ks * 64 + ((lane >> 4) << 4);
            short8 af[3], bfr[2];
            #pragma unroll
            for (int m = 0; m < 3; m++) {
                int r = wm * 48 + m * 16 + (lane & 15);
                af[m] = *(const short8*)(Ab + r * 128 + (cb ^ ((r & 7) << 4)));
            }
            #pragma unroll
            for (int n = 0; n < 2; n++) {
                int r = wn * 32 + n * 16 + (lane & 15);
                bfr[n] = *(const short8*)(Bb + r * 128 + (cb ^ ((r & 7) << 4)));
            }
            #pragma unroll
            for (int m = 0; m < 3; m++)
                #pragma unroll
                for (int n = 0; n < 2; n++)
                    acc[m][n] = __builtin_amdgcn_mfma_f32_16x16x32_bf16(af[m], bfr[n], acc[m][n], 0, 0, 0);
        }
        __syncthreads();
    }

    float* pb = partial + (size_t)blockIdx.x * (96 * 64);
    #pragma unroll
    for (int m = 0; m < 3; m++) {
        int rbase = wm * 48 + m * 16 + ((lane >> 4) << 2);
        #pragma unroll
        for (int n = 0; n < 2; n++) {
            int col = wn * 32 + n * 16 + (lane & 15);
            #pragma unroll
            for (int j = 0; j < 4; j++)
                pb[(rbase + j) * 64 + col] = acc[m][n][j];
        }
    }
}

// ---------------- finalize: full split-K reduction + bias + de-norm (one kernel) ----------------
__global__ void finalize(const float* __restrict__ partial, const float* __restrict__ hb,
                         const float* __restrict__ mean, const float* __restrict__ stdv,
                         float* __restrict__ out) {
    int i = blockIdx.x * 256 + threadIdx.x;
    if (i >= NB * 96 * CIN) return;
    int b = i / (96 * CIN);
    int r = i % (96 * CIN);
    int t = r / CIN, c = r % CIN;
    int bc = b * CIN + c;
    int j = t * 64 + bc;
    float s = 0.f;
    for (int blk = 0; blk < HNB; blk++) s += partial[(size_t)blk * 6144 + j];
    out[i] = (s + hb[t]) * stdv[bc] + mean[bc];
}

// ---------------- launch ----------------
extern "C" void kernel_launch(void* const* d_in, const int* in_sizes, int n_in,
                              void* d_out, int out_size, void* d_ws, size_t ws_size,
                              hipStream_t stream) {
    (void)in_sizes; (void)n_in; (void)out_size; (void)ws_size;
    const float* x_enc   = (const float*)d_in[0];
    const float* patch_W = (const float*)d_in[4];
    const float* Wq  = (const float*)d_in[5];
    const float* bq  = (const float*)d_in[6];
    const float* Wk  = (const float*)d_in[7];
    const float* bk  = (const float*)d_in[8];
    const float* Wv  = (const float*)d_in[9];
    const float* bv  = (const float*)d_in[10];
    const float* Wo  = (const float*)d_in[11];
    const float* bo  = (const float*)d_in[12];
    const float* c1W = (const float*)d_in[13];
    const float* c1b = (const float*)d_in[14];
    const float* c2W = (const float*)d_in[15];
    const float* c2b = (const float*)d_in[16];
    const float* ln1g = (const float*)d_in[17];
    const float* ln1b = (const float*)d_in[18];
    const float* ln2g = (const float*)d_in[19];
    const float* ln2b = (const float*)d_in[20];
    const float* encg = (const float*)d_in[21];
    const float* encb = (const float*)d_in[22];
    const float* headW = (const float*)d_in[23];
    const float* headb = (const float*)d_in[24];
    float* out = (float*)d_out;

    float* ws = (float*)d_ws;
    float* mean = ws + 0;
    float* stdv = ws + 64;
    float* bqkv = ws + 128;                 // 2*1536 floats
    int*   samp = (int*)(ws + 6144);        // 6400 ints
    size_t off = 32768;
    const size_t T = (size_t)NTOK * DM;     // 3,670,016
    float* partial = ws + off; off += T;      // head split-K partials (256*6144)
    // bf16 region
    short* sbase = (short*)(ws + off);
    size_t soff = 0;
    short* tok_b  = sbase + soff; soff += T;
    short* ctx_b  = sbase + soff; soff += T;
    short* x1_b   = sbase + soff; soff += T;
    short* pA_b   = sbase + soff; soff += T;
    short* qkv_b  = sbase + soff; soff += 3 * T;            // bf16 QKV
    short* ffn_b  = sbase + soff; soff += (size_t)NTOK * DFF;
    short* featb  = ffn_b;                  // reuse: ffn_b dead after encoder loop
    short* wqkv_b = sbase + soff; soff += 2 * 1536 * DM;
    short* wo_b   = sbase + soff; soff += 2 * DM * DM;
    short* c1w_b  = sbase + soff; soff += 2 * (size_t)DFF * DM;
    short* c2w_b  = sbase + soff; soff += 2 * (size_t)DM * DFF;

    prep_weights<<<6202, 256, 0, stream>>>(Wq, Wk, Wv, bq, bk, bv, Wo, c1W, c2W, x_enc,
                                           wqkv_b, bqkv, wo_b, c1w_b, c2w_b, samp, mean, stdv);
    patch_embed<<<dim3(NP, BC), 128, 0, stream>>>(x_enc, patch_W, mean, stdv, tok_b);

    for (int l = 0; l < 2; l++) {
        // QKV (bf16 out) — 64-row tile: 1344 blocks @3/CU -> 87.5% wave utilization
        gemm_mfma64<0><<<dim3(112, 12), 256, 0, stream>>>(tok_b, wqkv_b + (size_t)l * 1536 * DM, bqkv + l * 1536, nullptr, qkv_b, NTOK, 1536, DM);
        attn_fused<<<448, 256, 0, stream>>>(qkv_b, samp + l * 3200, ctx_b);
        // Wo + residual(tok_b) folded -> pA_b; then LN1 -> x1_b
        gemm_mfma64<1><<<dim3(112, 4), 256, 0, stream>>>(ctx_b, wo_b + (size_t)l * DM * DM, bo + l * DM, tok_b, pA_b, NTOK, DM, DM);
        ln4<<<NTOK / 4, 256, 0, stream>>>(pA_b, ln1g + l * DM, ln1b + l * DM, x1_b);
        gemm_mfma<1><<<dim3(56, 16), 256, 0, stream>>>(x1_b, c1w_b + (size_t)l * DFF * DM, c1b + l * DFF, ffn_b, NTOK, DFF, DM);
        // FFN2 + residual(x1_b) folded -> pA_b; then LN2 -> tok_b
        gemm_mfma64<1><<<dim3(112, 4), 256, 0, stream>>>(ffn_b, c2w_b + (size_t)l * DM * DFF, c2b + l * DM, x1_b, pA_b, NTOK, DM, DFF);
        ln4<<<NTOK / 4, 256, 0, stream>>>(pA_b, ln2g + l * DM, ln2b + l * DM, tok_b);
    }

    // final encoder LN fused with transpose -> featb
    ln_transpose<<<dim3(4, BC), 256, 0, stream>>>(tok_b, encg, encb, featb);
    head_mfma<<<HNB, 256, 0, stream>>>(headW, featb, partial);
    finalize<<<21, 256, 0, stream>>>(partial, headb, mean, stdv, out);
}